// Round 7
// baseline (1617.604 us; speedup 1.0000x reference)
//
#include <hip/hip_runtime.h>
#include <hip/hip_bf16.h>
#include <math.h>

typedef short s16x8 __attribute__((ext_vector_type(8)));
typedef float f32x4 __attribute__((ext_vector_type(4)));
typedef float f32x2 __attribute__((ext_vector_type(2)));

__device__ __forceinline__ float bflo(unsigned u) { return __uint_as_float(u << 16); }
__device__ __forceinline__ float bfhi(unsigned u) { return __uint_as_float(u & 0xffff0000u); }
__device__ __forceinline__ unsigned short f2bf(float f) {
    __hip_bfloat16 h = __float2bfloat16(f);
    return __builtin_bit_cast(unsigned short, h);
}
__device__ __forceinline__ f32x4 mfma_bf16(s16x8 a, s16x8 b, f32x4 c) {
    asm("v_mfma_f32_16x16x32_bf16 %0, %1, %2, %0" : "+v"(c) : "v"(a), "v"(b));
    return c;
}
// packed pair helpers (clang emits v_pk_* VOP3P for ext_vector float2)
__device__ __forceinline__ f32x2 unpk2(unsigned u) { return (f32x2){bflo(u), bfhi(u)}; }
__device__ __forceinline__ f32x2 plrelu(f32x2 x) {
    return __builtin_elementwise_max(x, x * 0.2f);
}

// ---------------- CSR build (sort edges by dst) ----------------
__global__ void degree_kernel(const int* __restrict__ dst, int* __restrict__ deg, int E) {
    int e = blockIdx.x * blockDim.x + threadIdx.x;
    if (e < E) atomicAdd(&deg[dst[e]], 1);
}

// single-pass blocked scan: 1 block, 1024 threads, ept elems/thread
__global__ __launch_bounds__(1024) void scan_kernel(const int* __restrict__ deg,
                                                    int* __restrict__ off, int n) {
    __shared__ int wsum[16];
    int t = threadIdx.x, lane = t & 63, w = t >> 6;
    int ept = (n + 1023) >> 10;
    int b0 = t * ept, b1 = min(b0 + ept, n);
    if (b0 > n) b0 = n;
    int sum = 0;
    for (int i = b0; i < b1; ++i) sum += deg[i];
    int x = sum;
    #pragma unroll
    for (int d = 1; d < 64; d <<= 1) { int y = __shfl_up(x, d); if (lane >= d) x += y; }
    if (lane == 63) wsum[w] = x;
    __syncthreads();
    if (t < 16) {
        int y = wsum[t];
        #pragma unroll
        for (int d = 1; d < 16; d <<= 1) { int z = __shfl_up(y, d); if (t >= d) y += z; }
        wsum[t] = y;
    }
    __syncthreads();
    int base = ((w == 0) ? 0 : wsum[w - 1]) + (x - sum);
    for (int i = b0; i < b1; ++i) { off[i] = base; base += deg[i]; }
    if (t == 1023) off[n] = base;
}

__global__ void scatter_kernel(const int* __restrict__ src, const int* __restrict__ dst,
                               const int* __restrict__ off, int* __restrict__ cursor,
                               int* __restrict__ ssrc, int E) {
    int e = blockIdx.x * blockDim.x + threadIdx.x;
    if (e < E) {
        int d = dst[e];
        int pos = off[d] + atomicAdd(&cursor[d], 1);
        ssrc[pos] = src[e];
    }
}

// ---------------- weight prep (both layers, one launch) ----------------
__global__ void wt_prep_kernel(const float* __restrict__ Wl1, const float* __restrict__ Wr1,
                               const float* __restrict__ Wl2, const float* __restrict__ Wr2,
                               unsigned short* __restrict__ Wt1, unsigned short* __restrict__ Wt2) {
    int idx = blockIdx.x * 256 + threadIdx.x;
    if (idx < 256 * 128) {
        int n = idx >> 7, k = idx & 127;
        float v = (n < 128) ? Wl1[k * 128 + n] : Wr1[k * 128 + (n - 128)];
        Wt1[idx] = f2bf(v);
    } else if (idx < 256 * 128 + 128 * 128) {
        int j = idx - 256 * 128;
        int n = j >> 7, k = j & 127;
        float v = (n < 64) ? Wl2[k * 64 + n] : Wr2[k * 64 + (n - 64)];
        Wt2[j] = f2bf(v);
    }
}

// ---------------- MFMA dual GEMM (unchanged from r5) ----------------
template <int NOUT, bool AFP32>
__global__ __launch_bounds__(256) void mfma_gemm_kernel(
    const void* __restrict__ A, const unsigned short* __restrict__ Wt,
    unsigned short* __restrict__ Cl, unsigned short* __restrict__ Cr, int nrows) {
    constexpr int HALF = NOUT / 2;
    constexpr int CT = NOUT / 64;
    __shared__ unsigned short As[64 * 128];
    int t = threadIdx.x, lane = t & 63, wave = t >> 6;
    int row_base = blockIdx.x * 64;
    int rows_here = nrows - row_base;
    #pragma unroll
    for (int it = 0; it < 4; ++it) {
        int q = it * 256 + t;
        int r = q >> 4, c8 = q & 15;
        int su = r * 16 + (c8 ^ (r & 7));
        s16x8 v = {0, 0, 0, 0, 0, 0, 0, 0};
        if (r < rows_here) {
            if (AFP32) {
                const float4* g = reinterpret_cast<const float4*>(
                    (const float*)A + ((size_t)(row_base + r)) * 128 + c8 * 8);
                float4 v0 = g[0], v1 = g[1];
                union { s16x8 s; unsigned short u[8]; } pk;
                pk.u[0] = f2bf(v0.x); pk.u[1] = f2bf(v0.y);
                pk.u[2] = f2bf(v0.z); pk.u[3] = f2bf(v0.w);
                pk.u[4] = f2bf(v1.x); pk.u[5] = f2bf(v1.y);
                pk.u[6] = f2bf(v1.z); pk.u[7] = f2bf(v1.w);
                v = pk.s;
            } else {
                v = *reinterpret_cast<const s16x8*>(
                    (const unsigned short*)A + ((size_t)(row_base + r)) * 128 + c8 * 8);
            }
        }
        reinterpret_cast<s16x8*>(As)[su] = v;
    }
    __syncthreads();
    int m16 = lane & 15, kg = lane >> 4;
    int colw = wave * (NOUT / 4);
    s16x8 bfr[CT][4];
    const s16x8* Wt16 = reinterpret_cast<const s16x8*>(Wt);
    #pragma unroll
    for (int ct = 0; ct < CT; ++ct)
        #pragma unroll
        for (int ks = 0; ks < 4; ++ks)
            bfr[ct][ks] = Wt16[(size_t)(colw + ct * 16 + m16) * 16 + ks * 4 + kg];
    f32x4 acc[4][CT];
    #pragma unroll
    for (int rt = 0; rt < 4; ++rt)
        #pragma unroll
        for (int ct = 0; ct < CT; ++ct) acc[rt][ct] = (f32x4){0.f, 0.f, 0.f, 0.f};
    const s16x8* As16 = reinterpret_cast<const s16x8*>(As);
    int sw = m16 & 7;
    #pragma unroll
    for (int rt = 0; rt < 4; ++rt) {
        int abase = (rt * 16 + m16) * 16;
        #pragma unroll
        for (int ks = 0; ks < 4; ++ks) {
            s16x8 af = As16[abase + ((ks * 4 + kg) ^ sw)];
            #pragma unroll
            for (int ct = 0; ct < CT; ++ct)
                acc[rt][ct] = mfma_bf16(af, bfr[ct][ks], acc[rt][ct]);
        }
    }
    int rq = kg * 4;
    #pragma unroll
    for (int rt = 0; rt < 4; ++rt) {
        #pragma unroll
        for (int ct = 0; ct < CT; ++ct) {
            int n = colw + ct * 16 + m16;
            unsigned short* Cp = (n < HALF) ? (Cl + n) : (Cr + (n - HALF));
            int row0 = row_base + rt * 16 + rq;
            #pragma unroll
            for (int i = 0; i < 4; ++i) {
                int row = row0 + i;
                if (row < nrows) Cp[(size_t)row * HALF] = f2bf(acc[rt][ct][i]);
            }
        }
    }
}

// ---------------- GAT layer 1 (r5 layout + pk math + work stealing) ----------------
// lane l: head h = l>>3, features i0 = h*16+2*(l&7), i0+1. One dword gather/edge,
// 3-stage 8-lane reduce, single exp. Persistent waves steal nodes via counter.
__global__ __launch_bounds__(256) void gat1_kernel(
    const unsigned short* __restrict__ xl, const unsigned short* __restrict__ xr,
    const int* __restrict__ off, const int* __restrict__ ssrc,
    const float* __restrict__ att, const float* __restrict__ bias,
    const float* __restrict__ gamma, const float* __restrict__ beta,
    unsigned short* __restrict__ out, int* __restrict__ counter, int n) {
    int lane = threadIdx.x & 63;
    int h = lane >> 3;
    int i0 = h * 16 + ((lane & 7) << 1);
    for (;;) {
        int node;
        if (lane == 0) node = atomicAdd(counter, 1);
        node = __shfl(node, 0);
        if (node >= n) break;
        f32x2 xrp = unpk2(*reinterpret_cast<const unsigned*>(xr + (size_t)node * 128 + i0));
        f32x2 atp = {att[i0], att[i0 + 1]};
        float s = 0.f;
        f32x2 ac = {0.f, 0.f};
        int beg = off[node], end = off[node + 1];
        int i = beg;
        for (; i + 4 <= end; i += 4) {
            int e0 = ssrc[i], e1 = ssrc[i + 1], e2 = ssrc[i + 2], e3 = ssrc[i + 3];
            unsigned u0 = *reinterpret_cast<const unsigned*>(xl + (size_t)e0 * 128 + i0);
            unsigned u1 = *reinterpret_cast<const unsigned*>(xl + (size_t)e1 * 128 + i0);
            unsigned u2 = *reinterpret_cast<const unsigned*>(xl + (size_t)e2 * 128 + i0);
            unsigned u3 = *reinterpret_cast<const unsigned*>(xl + (size_t)e3 * 128 + i0);
            f32x2 x0 = unpk2(u0), x1 = unpk2(u1), x2 = unpk2(u2), x3 = unpk2(u3);
            f32x2 q0 = plrelu(x0 + xrp) * atp;
            f32x2 q1 = plrelu(x1 + xrp) * atp;
            f32x2 q2 = plrelu(x2 + xrp) * atp;
            f32x2 q3 = plrelu(x3 + xrp) * atp;
            float p0 = q0.x + q0.y, p1 = q1.x + q1.y;
            float p2 = q2.x + q2.y, p3 = q3.x + q3.y;
            #pragma unroll
            for (int d = 1; d < 8; d <<= 1) {
                p0 += __shfl_xor(p0, d); p1 += __shfl_xor(p1, d);
                p2 += __shfl_xor(p2, d); p3 += __shfl_xor(p3, d);
            }
            float w0 = __expf(fminf(p0, 60.f));
            float w1 = __expf(fminf(p1, 60.f));
            float w2 = __expf(fminf(p2, 60.f));
            float w3 = __expf(fminf(p3, 60.f));
            s += (w0 + w1) + (w2 + w3);
            ac += w0 * x0 + w1 * x1;
            ac += w2 * x2 + w3 * x3;
        }
        for (; i < end; ++i) {
            int e = ssrc[i];
            f32x2 xv = unpk2(*reinterpret_cast<const unsigned*>(xl + (size_t)e * 128 + i0));
            f32x2 q = plrelu(xv + xrp) * atp;
            float p = q.x + q.y;
            #pragma unroll
            for (int d = 1; d < 8; d <<= 1) p += __shfl_xor(p, d);
            float w = __expf(fminf(p, 60.f));
            s += w; ac += w * xv;
        }
        float inv = 1.f / (s + 1e-16f);
        float o0 = ac.x * inv + bias[i0];
        float o1 = ac.y * inv + bias[i0 + 1];
        float tsum = o0 + o1;
        #pragma unroll
        for (int d = 1; d < 64; d <<= 1) tsum += __shfl_xor(tsum, d);
        float mu = tsum * (1.f / 128.f);
        float d0 = o0 - mu, d1 = o1 - mu;
        float vsum = d0 * d0 + d1 * d1;
        #pragma unroll
        for (int d = 1; d < 64; d <<= 1) vsum += __shfl_xor(vsum, d);
        float rs = rsqrtf(vsum * (1.f / 128.f) + 1e-5f);
        float y0 = d0 * rs * gamma[i0] + beta[i0];
        float y1 = d1 * rs * gamma[i0 + 1] + beta[i0 + 1];
        y0 = y0 > 0.f ? y0 : expm1f(y0);
        y1 = y1 > 0.f ? y1 : expm1f(y1);
        unsigned pk = (unsigned)f2bf(y0) | ((unsigned)f2bf(y1) << 16);
        *reinterpret_cast<unsigned*>(out + (size_t)node * 128 + i0) = pk;
    }
}

// ---------------- GAT layer 2 (r5 layout + pk math + work stealing) ----------------
__global__ __launch_bounds__(256) void gat2_kernel(
    const unsigned short* __restrict__ xl, const unsigned short* __restrict__ xr,
    const int* __restrict__ off, const int* __restrict__ ssrc,
    const float* __restrict__ att, const float* __restrict__ bias,
    const float* __restrict__ gamma, const float* __restrict__ beta,
    float* __restrict__ out, int* __restrict__ counter, int n) {
    int lane = threadIdx.x & 63;
    int half = lane >> 5;
    int c2 = (lane & 31) << 1;
    for (;;) {
        int node;
        if (lane == 0) node = atomicAdd(counter, 1);
        node = __shfl(node, 0);
        if (node >= n) break;
        f32x2 xrp = unpk2(*reinterpret_cast<const unsigned*>(xr + (size_t)node * 64 + c2));
        f32x2 atp = {att[c2], att[c2 + 1]};
        float s = 0.f;
        f32x2 ac = {0.f, 0.f};
        int beg = off[node], end = off[node + 1];
        int i = beg;
        for (; i + 4 <= end; i += 4) {
            int eA = ssrc[i + half], eB = ssrc[i + 2 + half];
            f32x2 xA = unpk2(*reinterpret_cast<const unsigned*>(xl + (size_t)eA * 64 + c2));
            f32x2 xB = unpk2(*reinterpret_cast<const unsigned*>(xl + (size_t)eB * 64 + c2));
            f32x2 qA = plrelu(xA + xrp) * atp;
            f32x2 qB = plrelu(xB + xrp) * atp;
            float pA = qA.x + qA.y, pB = qB.x + qB.y;
            #pragma unroll
            for (int d = 1; d < 32; d <<= 1) {
                pA += __shfl_xor(pA, d); pB += __shfl_xor(pB, d);
            }
            float wA = __expf(fminf(pA, 60.f));
            float wB = __expf(fminf(pB, 60.f));
            s += wA + wB;
            ac += wA * xA + wB * xB;
        }
        for (; i < end; i += 2) {
            int e = i + half;
            bool valid = e < end;
            int se = ssrc[valid ? e : i];
            f32x2 xv = unpk2(*reinterpret_cast<const unsigned*>(xl + (size_t)se * 64 + c2));
            f32x2 q = plrelu(xv + xrp) * atp;
            float p = q.x + q.y;
            #pragma unroll
            for (int d = 1; d < 32; d <<= 1) p += __shfl_xor(p, d);
            float w = valid ? __expf(fminf(p, 60.f)) : 0.f;
            s += w; ac += w * xv;
        }
        s += __shfl_xor(s, 32);
        f32x2 aco = {__shfl_xor(ac.x, 32), __shfl_xor(ac.y, 32)};
        ac += aco;
        float inv = 1.f / (s + 1e-16f);
        float o0 = ac.x * inv + bias[c2];
        float o1 = ac.y * inv + bias[c2 + 1];
        float tsum = o0 + o1;
        #pragma unroll
        for (int d = 1; d < 32; d <<= 1) tsum += __shfl_xor(tsum, d);
        float mu = tsum * (1.f / 64.f);
        float d0 = o0 - mu, d1 = o1 - mu;
        float vsum = d0 * d0 + d1 * d1;
        #pragma unroll
        for (int d = 1; d < 32; d <<= 1) vsum += __shfl_xor(vsum, d);
        float rs = rsqrtf(vsum * (1.f / 64.f) + 1e-5f);
        if (half == 0) {
            float y0 = d0 * rs * gamma[c2] + beta[c2];
            float y1 = d1 * rs * gamma[c2 + 1] + beta[c2 + 1];
            *reinterpret_cast<float2*>(out + (size_t)node * 64 + c2) = make_float2(y0, y1);
        }
    }
}

extern "C" void kernel_launch(void* const* d_in, const int* in_sizes, int n_in,
                              void* d_out, int out_size, void* d_ws, size_t ws_size,
                              hipStream_t stream) {
    const float* x = (const float*)d_in[0];
    const int* ei = (const int*)d_in[1];
    const float* Wl1 = (const float*)d_in[2];
    const float* Wr1 = (const float*)d_in[3];
    const float* att1 = (const float*)d_in[4];
    const float* bias1 = (const float*)d_in[5];
    const float* g1 = (const float*)d_in[6];
    const float* b1 = (const float*)d_in[7];
    const float* Wl2 = (const float*)d_in[8];
    const float* Wr2 = (const float*)d_in[9];
    const float* att2 = (const float*)d_in[10];
    const float* bias2 = (const float*)d_in[11];
    const float* g2 = (const float*)d_in[12];
    const float* b2 = (const float*)d_in[13];
    float* out = (float*)d_out;

    const int N = in_sizes[0] / 128;
    const int E = in_sizes[1] / 2;
    const int* src = ei;
    const int* dstp = ei + E;

    char* p = (char*)d_ws;
    auto alloc = [&](size_t bytes) -> char* {
        char* r = p;
        p += (bytes + 255) & ~(size_t)255;
        return r;
    };
    int* counters = (int*)alloc(256);  // [0]=gat1, [1]=gat2
    int* deg = (int*)alloc((size_t)N * 4);
    int* cursor = (int*)alloc((size_t)N * 4);
    int* off = (int*)alloc((size_t)(N + 1) * 4);
    int* ssrc = (int*)alloc((size_t)E * 4);
    unsigned short* Wt1 = (unsigned short*)alloc(256 * 128 * 2);
    unsigned short* Wt2 = (unsigned short*)alloc(128 * 128 * 2);
    unsigned short* bufA = (unsigned short*)alloc((size_t)N * 128 * 2);
    unsigned short* bufB = (unsigned short*)alloc((size_t)N * 128 * 2);
    unsigned short* h1u = (unsigned short*)alloc((size_t)N * 128 * 2);

    hipMemsetAsync(counters, 0, 256, stream);
    hipMemsetAsync(deg, 0, (size_t)N * 4, stream);
    hipMemsetAsync(cursor, 0, (size_t)N * 4, stream);
    degree_kernel<<<(E + 255) / 256, 256, 0, stream>>>(dstp, deg, E);
    wt_prep_kernel<<<(256 * 128 + 128 * 128 + 255) / 256, 256, 0, stream>>>(
        Wl1, Wr1, Wl2, Wr2, Wt1, Wt2);
    scan_kernel<<<1, 1024, 0, stream>>>(deg, off, N);
    scatter_kernel<<<(E + 255) / 256, 256, 0, stream>>>(src, dstp, off, cursor, ssrc, E);

    int gblocks = (N + 63) / 64;
    mfma_gemm_kernel<256, true><<<gblocks, 256, 0, stream>>>(x, Wt1, bufA, bufB, N);
    gat1_kernel<<<2048, 256, 0, stream>>>(bufA, bufB, off, ssrc, att1, bias1, g1, b1,
                                          h1u, counters + 0, N);
    mfma_gemm_kernel<128, false><<<gblocks, 256, 0, stream>>>(h1u, Wt2, bufA, bufB, N);
    gat2_kernel<<<2048, 256, 0, stream>>>(bufA, bufB, off, ssrc, att2, bias2, g2, b2,
                                          out, counters + 1, N);
}

// Round 8
// 320.772 us; speedup vs baseline: 5.0428x; 5.0428x over previous
//
#include <hip/hip_runtime.h>
#include <hip/hip_bf16.h>
#include <math.h>

typedef short s16x8 __attribute__((ext_vector_type(8)));
typedef float f32x4 __attribute__((ext_vector_type(4)));
typedef float f32x2 __attribute__((ext_vector_type(2)));

__device__ __forceinline__ float bflo(unsigned u) { return __uint_as_float(u << 16); }
__device__ __forceinline__ float bfhi(unsigned u) { return __uint_as_float(u & 0xffff0000u); }
__device__ __forceinline__ unsigned short f2bf(float f) {
    __hip_bfloat16 h = __float2bfloat16(f);
    return __builtin_bit_cast(unsigned short, h);
}
__device__ __forceinline__ f32x4 mfma_bf16(s16x8 a, s16x8 b, f32x4 c) {
    asm("v_mfma_f32_16x16x32_bf16 %0, %1, %2, %0" : "+v"(c) : "v"(a), "v"(b));
    return c;
}
__device__ __forceinline__ f32x2 unpk2(unsigned u) { return (f32x2){bflo(u), bfhi(u)}; }
__device__ __forceinline__ f32x2 plrelu(f32x2 x) {
    return __builtin_elementwise_max(x, x * 0.2f);
}

// ---------------- CSR build (sort edges by dst) ----------------
__global__ void degree_kernel(const int* __restrict__ dst, int* __restrict__ deg, int E) {
    int e = blockIdx.x * blockDim.x + threadIdx.x;
    if (e < E) atomicAdd(&deg[dst[e]], 1);
}

// multi-round coalesced scan (r6 version — proven)
__global__ __launch_bounds__(1024) void scan_kernel(const int* __restrict__ deg,
                                                    int* __restrict__ off, int n) {
    __shared__ int wsum[16];
    __shared__ int s_carry;
    int t = threadIdx.x, lane = t & 63, w = t >> 6;
    if (t == 0) s_carry = 0;
    __syncthreads();
    for (int base = 0; base < n; base += 4096) {
        int i = base + t * 4;
        int4 v = make_int4(0, 0, 0, 0);
        if (i + 3 < n) v = *reinterpret_cast<const int4*>(&deg[i]);
        else {
            if (i < n) v.x = deg[i];
            if (i + 1 < n) v.y = deg[i + 1];
            if (i + 2 < n) v.z = deg[i + 2];
        }
        int tsum = v.x + v.y + v.z + v.w;
        int x = tsum;
        #pragma unroll
        for (int d = 1; d < 64; d <<= 1) { int y = __shfl_up(x, d); if (lane >= d) x += y; }
        if (lane == 63) wsum[w] = x;
        __syncthreads();
        if (w == 0 && lane < 16) {
            int y = wsum[lane];
            #pragma unroll
            for (int d = 1; d < 16; d <<= 1) { int z = __shfl_up(y, d); if (lane >= d) y += z; }
            wsum[lane] = y;
        }
        __syncthreads();
        int excl = s_carry + ((w == 0) ? 0 : wsum[w - 1]) + (x - tsum);
        if (i < n) off[i] = excl;
        if (i + 1 < n) off[i + 1] = excl + v.x;
        if (i + 2 < n) off[i + 2] = excl + v.x + v.y;
        if (i + 3 < n) off[i + 3] = excl + v.x + v.y + v.z;
        __syncthreads();
        if (t == 0) s_carry += wsum[15];
        __syncthreads();
    }
    if (t == 0) off[n] = s_carry;
}

__global__ void scatter_kernel(const int* __restrict__ src, const int* __restrict__ dst,
                               const int* __restrict__ off, int* __restrict__ cursor,
                               int* __restrict__ ssrc, int E) {
    int e = blockIdx.x * blockDim.x + threadIdx.x;
    if (e < E) {
        int d = dst[e];
        int pos = off[d] + atomicAdd(&cursor[d], 1);
        ssrc[pos] = src[e];
    }
}

// ---------------- weight prep (both layers, one launch) ----------------
__global__ void wt_prep_kernel(const float* __restrict__ Wl1, const float* __restrict__ Wr1,
                               const float* __restrict__ Wl2, const float* __restrict__ Wr2,
                               unsigned short* __restrict__ Wt1, unsigned short* __restrict__ Wt2) {
    int idx = blockIdx.x * 256 + threadIdx.x;
    if (idx < 256 * 128) {
        int n = idx >> 7, k = idx & 127;
        float v = (n < 128) ? Wl1[k * 128 + n] : Wr1[k * 128 + (n - 128)];
        Wt1[idx] = f2bf(v);
    } else if (idx < 256 * 128 + 128 * 128) {
        int j = idx - 256 * 128;
        int n = j >> 7, k = j & 127;
        float v = (n < 64) ? Wl2[k * 64 + n] : Wr2[k * 64 + (n - 64)];
        Wt2[j] = f2bf(v);
    }
}

// ---------------- MFMA dual GEMM (unchanged from r5) ----------------
template <int NOUT, bool AFP32>
__global__ __launch_bounds__(256) void mfma_gemm_kernel(
    const void* __restrict__ A, const unsigned short* __restrict__ Wt,
    unsigned short* __restrict__ Cl, unsigned short* __restrict__ Cr, int nrows) {
    constexpr int HALF = NOUT / 2;
    constexpr int CT = NOUT / 64;
    __shared__ unsigned short As[64 * 128];
    int t = threadIdx.x, lane = t & 63, wave = t >> 6;
    int row_base = blockIdx.x * 64;
    int rows_here = nrows - row_base;
    #pragma unroll
    for (int it = 0; it < 4; ++it) {
        int q = it * 256 + t;
        int r = q >> 4, c8 = q & 15;
        int su = r * 16 + (c8 ^ (r & 7));
        s16x8 v = {0, 0, 0, 0, 0, 0, 0, 0};
        if (r < rows_here) {
            if (AFP32) {
                const float4* g = reinterpret_cast<const float4*>(
                    (const float*)A + ((size_t)(row_base + r)) * 128 + c8 * 8);
                float4 v0 = g[0], v1 = g[1];
                union { s16x8 s; unsigned short u[8]; } pk;
                pk.u[0] = f2bf(v0.x); pk.u[1] = f2bf(v0.y);
                pk.u[2] = f2bf(v0.z); pk.u[3] = f2bf(v0.w);
                pk.u[4] = f2bf(v1.x); pk.u[5] = f2bf(v1.y);
                pk.u[6] = f2bf(v1.z); pk.u[7] = f2bf(v1.w);
                v = pk.s;
            } else {
                v = *reinterpret_cast<const s16x8*>(
                    (const unsigned short*)A + ((size_t)(row_base + r)) * 128 + c8 * 8);
            }
        }
        reinterpret_cast<s16x8*>(As)[su] = v;
    }
    __syncthreads();
    int m16 = lane & 15, kg = lane >> 4;
    int colw = wave * (NOUT / 4);
    s16x8 bfr[CT][4];
    const s16x8* Wt16 = reinterpret_cast<const s16x8*>(Wt);
    #pragma unroll
    for (int ct = 0; ct < CT; ++ct)
        #pragma unroll
        for (int ks = 0; ks < 4; ++ks)
            bfr[ct][ks] = Wt16[(size_t)(colw + ct * 16 + m16) * 16 + ks * 4 + kg];
    f32x4 acc[4][CT];
    #pragma unroll
    for (int rt = 0; rt < 4; ++rt)
        #pragma unroll
        for (int ct = 0; ct < CT; ++ct) acc[rt][ct] = (f32x4){0.f, 0.f, 0.f, 0.f};
    const s16x8* As16 = reinterpret_cast<const s16x8*>(As);
    int sw = m16 & 7;
    #pragma unroll
    for (int rt = 0; rt < 4; ++rt) {
        int abase = (rt * 16 + m16) * 16;
        #pragma unroll
        for (int ks = 0; ks < 4; ++ks) {
            s16x8 af = As16[abase + ((ks * 4 + kg) ^ sw)];
            #pragma unroll
            for (int ct = 0; ct < CT; ++ct)
                acc[rt][ct] = mfma_bf16(af, bfr[ct][ks], acc[rt][ct]);
        }
    }
    int rq = kg * 4;
    #pragma unroll
    for (int rt = 0; rt < 4; ++rt) {
        #pragma unroll
        for (int ct = 0; ct < CT; ++ct) {
            int n = colw + ct * 16 + m16;
            unsigned short* Cp = (n < HALF) ? (Cl + n) : (Cr + (n - HALF));
            int row0 = row_base + rt * 16 + rq;
            #pragma unroll
            for (int i = 0; i < 4; ++i) {
                int row = row0 + i;
                if (row < nrows) Cp[(size_t)row * HALF] = f2bf(acc[rt][ct][i]);
            }
        }
    }
}

// ---------------- GAT layer 1 (r5 layout, static nodes, pk math) ----------------
// lane l: head h = l>>3, features i0 = h*16+2*(l&7), i0+1. One dword gather/edge,
// 3-stage 8-lane reduce, single exp.
__global__ __launch_bounds__(256) void gat1_kernel(
    const unsigned short* __restrict__ xl, const unsigned short* __restrict__ xr,
    const int* __restrict__ off, const int* __restrict__ ssrc,
    const float* __restrict__ att, const float* __restrict__ bias,
    const float* __restrict__ gamma, const float* __restrict__ beta,
    unsigned short* __restrict__ out, int n) {
    int lane = threadIdx.x & 63;
    int node = blockIdx.x * 4 + (threadIdx.x >> 6);
    if (node >= n) return;
    int h = lane >> 3;
    int i0 = h * 16 + ((lane & 7) << 1);
    f32x2 xrp = unpk2(*reinterpret_cast<const unsigned*>(xr + (size_t)node * 128 + i0));
    f32x2 atp = {att[i0], att[i0 + 1]};
    float s = 0.f;
    f32x2 ac = {0.f, 0.f};
    int beg = off[node], end = off[node + 1];
    int i = beg;
    for (; i + 4 <= end; i += 4) {
        int e0 = ssrc[i], e1 = ssrc[i + 1], e2 = ssrc[i + 2], e3 = ssrc[i + 3];
        unsigned u0 = *reinterpret_cast<const unsigned*>(xl + (size_t)e0 * 128 + i0);
        unsigned u1 = *reinterpret_cast<const unsigned*>(xl + (size_t)e1 * 128 + i0);
        unsigned u2 = *reinterpret_cast<const unsigned*>(xl + (size_t)e2 * 128 + i0);
        unsigned u3 = *reinterpret_cast<const unsigned*>(xl + (size_t)e3 * 128 + i0);
        f32x2 x0 = unpk2(u0), x1 = unpk2(u1), x2 = unpk2(u2), x3 = unpk2(u3);
        f32x2 q0 = plrelu(x0 + xrp) * atp;
        f32x2 q1 = plrelu(x1 + xrp) * atp;
        f32x2 q2 = plrelu(x2 + xrp) * atp;
        f32x2 q3 = plrelu(x3 + xrp) * atp;
        float p0 = q0.x + q0.y, p1 = q1.x + q1.y;
        float p2 = q2.x + q2.y, p3 = q3.x + q3.y;
        #pragma unroll
        for (int d = 1; d < 8; d <<= 1) {
            p0 += __shfl_xor(p0, d); p1 += __shfl_xor(p1, d);
            p2 += __shfl_xor(p2, d); p3 += __shfl_xor(p3, d);
        }
        float w0 = __expf(fminf(p0, 60.f));
        float w1 = __expf(fminf(p1, 60.f));
        float w2 = __expf(fminf(p2, 60.f));
        float w3 = __expf(fminf(p3, 60.f));
        s += (w0 + w1) + (w2 + w3);
        ac += w0 * x0 + w1 * x1;
        ac += w2 * x2 + w3 * x3;
    }
    for (; i < end; ++i) {
        int e = ssrc[i];
        f32x2 xv = unpk2(*reinterpret_cast<const unsigned*>(xl + (size_t)e * 128 + i0));
        f32x2 q = plrelu(xv + xrp) * atp;
        float p = q.x + q.y;
        #pragma unroll
        for (int d = 1; d < 8; d <<= 1) p += __shfl_xor(p, d);
        float w = __expf(fminf(p, 60.f));
        s += w; ac += w * xv;
    }
    float inv = 1.f / (s + 1e-16f);
    float o0 = ac.x * inv + bias[i0];
    float o1 = ac.y * inv + bias[i0 + 1];
    float tsum = o0 + o1;
    #pragma unroll
    for (int d = 1; d < 64; d <<= 1) tsum += __shfl_xor(tsum, d);
    float mu = tsum * (1.f / 128.f);
    float d0 = o0 - mu, d1 = o1 - mu;
    float vsum = d0 * d0 + d1 * d1;
    #pragma unroll
    for (int d = 1; d < 64; d <<= 1) vsum += __shfl_xor(vsum, d);
    float rs = rsqrtf(vsum * (1.f / 128.f) + 1e-5f);
    float y0 = d0 * rs * gamma[i0] + beta[i0];
    float y1 = d1 * rs * gamma[i0 + 1] + beta[i0 + 1];
    y0 = y0 > 0.f ? y0 : expm1f(y0);
    y1 = y1 > 0.f ? y1 : expm1f(y1);
    unsigned pk = (unsigned)f2bf(y0) | ((unsigned)f2bf(y1) << 16);
    *reinterpret_cast<unsigned*>(out + (size_t)node * 128 + i0) = pk;
}

// ---------------- GAT layer 2 (r5 layout, static nodes, pk math) ----------------
__global__ __launch_bounds__(256) void gat2_kernel(
    const unsigned short* __restrict__ xl, const unsigned short* __restrict__ xr,
    const int* __restrict__ off, const int* __restrict__ ssrc,
    const float* __restrict__ att, const float* __restrict__ bias,
    const float* __restrict__ gamma, const float* __restrict__ beta,
    float* __restrict__ out, int n) {
    int lane = threadIdx.x & 63;
    int node = blockIdx.x * 4 + (threadIdx.x >> 6);
    if (node >= n) return;
    int half = lane >> 5;
    int c2 = (lane & 31) << 1;
    f32x2 xrp = unpk2(*reinterpret_cast<const unsigned*>(xr + (size_t)node * 64 + c2));
    f32x2 atp = {att[c2], att[c2 + 1]};
    float s = 0.f;
    f32x2 ac = {0.f, 0.f};
    int beg = off[node], end = off[node + 1];
    int i = beg;
    for (; i + 4 <= end; i += 4) {
        int eA = ssrc[i + half], eB = ssrc[i + 2 + half];
        f32x2 xA = unpk2(*reinterpret_cast<const unsigned*>(xl + (size_t)eA * 64 + c2));
        f32x2 xB = unpk2(*reinterpret_cast<const unsigned*>(xl + (size_t)eB * 64 + c2));
        f32x2 qA = plrelu(xA + xrp) * atp;
        f32x2 qB = plrelu(xB + xrp) * atp;
        float pA = qA.x + qA.y, pB = qB.x + qB.y;
        #pragma unroll
        for (int d = 1; d < 32; d <<= 1) {
            pA += __shfl_xor(pA, d); pB += __shfl_xor(pB, d);
        }
        float wA = __expf(fminf(pA, 60.f));
        float wB = __expf(fminf(pB, 60.f));
        s += wA + wB;
        ac += wA * xA + wB * xB;
    }
    for (; i < end; i += 2) {
        int e = i + half;
        bool valid = e < end;
        int se = ssrc[valid ? e : i];
        f32x2 xv = unpk2(*reinterpret_cast<const unsigned*>(xl + (size_t)se * 64 + c2));
        f32x2 q = plrelu(xv + xrp) * atp;
        float p = q.x + q.y;
        #pragma unroll
        for (int d = 1; d < 32; d <<= 1) p += __shfl_xor(p, d);
        float w = valid ? __expf(fminf(p, 60.f)) : 0.f;
        s += w; ac += w * xv;
    }
    s += __shfl_xor(s, 32);
    f32x2 aco = {__shfl_xor(ac.x, 32), __shfl_xor(ac.y, 32)};
    ac += aco;
    float inv = 1.f / (s + 1e-16f);
    float o0 = ac.x * inv + bias[c2];
    float o1 = ac.y * inv + bias[c2 + 1];
    float tsum = o0 + o1;
    #pragma unroll
    for (int d = 1; d < 32; d <<= 1) tsum += __shfl_xor(tsum, d);
    float mu = tsum * (1.f / 64.f);
    float d0 = o0 - mu, d1 = o1 - mu;
    float vsum = d0 * d0 + d1 * d1;
    #pragma unroll
    for (int d = 1; d < 32; d <<= 1) vsum += __shfl_xor(vsum, d);
    float rs = rsqrtf(vsum * (1.f / 64.f) + 1e-5f);
    if (half == 0) {
        float y0 = d0 * rs * gamma[c2] + beta[c2];
        float y1 = d1 * rs * gamma[c2 + 1] + beta[c2 + 1];
        *reinterpret_cast<float2*>(out + (size_t)node * 64 + c2) = make_float2(y0, y1);
    }
}

extern "C" void kernel_launch(void* const* d_in, const int* in_sizes, int n_in,
                              void* d_out, int out_size, void* d_ws, size_t ws_size,
                              hipStream_t stream) {
    const float* x = (const float*)d_in[0];
    const int* ei = (const int*)d_in[1];
    const float* Wl1 = (const float*)d_in[2];
    const float* Wr1 = (const float*)d_in[3];
    const float* att1 = (const float*)d_in[4];
    const float* bias1 = (const float*)d_in[5];
    const float* g1 = (const float*)d_in[6];
    const float* b1 = (const float*)d_in[7];
    const float* Wl2 = (const float*)d_in[8];
    const float* Wr2 = (const float*)d_in[9];
    const float* att2 = (const float*)d_in[10];
    const float* bias2 = (const float*)d_in[11];
    const float* g2 = (const float*)d_in[12];
    const float* b2 = (const float*)d_in[13];
    float* out = (float*)d_out;

    const int N = in_sizes[0] / 128;
    const int E = in_sizes[1] / 2;
    const int* src = ei;
    const int* dstp = ei + E;

    char* p = (char*)d_ws;
    auto alloc = [&](size_t bytes) -> char* {
        char* r = p;
        p += (bytes + 255) & ~(size_t)255;
        return r;
    };
    int* deg = (int*)alloc((size_t)N * 4);
    int* cursor = (int*)alloc((size_t)N * 4);
    int* off = (int*)alloc((size_t)(N + 1) * 4);
    int* ssrc = (int*)alloc((size_t)E * 4);
    unsigned short* Wt1 = (unsigned short*)alloc(256 * 128 * 2);
    unsigned short* Wt2 = (unsigned short*)alloc(128 * 128 * 2);
    unsigned short* bufA = (unsigned short*)alloc((size_t)N * 128 * 2);
    unsigned short* bufB = (unsigned short*)alloc((size_t)N * 128 * 2);
    unsigned short* h1u = (unsigned short*)alloc((size_t)N * 128 * 2);

    hipMemsetAsync(deg, 0, (size_t)N * 4, stream);
    hipMemsetAsync(cursor, 0, (size_t)N * 4, stream);
    degree_kernel<<<(E + 255) / 256, 256, 0, stream>>>(dstp, deg, E);
    wt_prep_kernel<<<(256 * 128 + 128 * 128 + 255) / 256, 256, 0, stream>>>(
        Wl1, Wr1, Wl2, Wr2, Wt1, Wt2);
    scan_kernel<<<1, 1024, 0, stream>>>(deg, off, N);
    scatter_kernel<<<(E + 255) / 256, 256, 0, stream>>>(src, dstp, off, cursor, ssrc, E);

    int gblocks = (N + 63) / 64;
    mfma_gemm_kernel<256, true><<<gblocks, 256, 0, stream>>>(x, Wt1, bufA, bufB, N);
    gat1_kernel<<<(N + 3) / 4, 256, 0, stream>>>(bufA, bufB, off, ssrc, att1, bias1, g1, b1, h1u, N);
    mfma_gemm_kernel<128, false><<<gblocks, 256, 0, stream>>>(h1u, Wt2, bufA, bufB, N);
    gat2_kernel<<<(N + 3) / 4, 256, 0, stream>>>(bufA, bufB, off, ssrc, att2, bias2, g2, b2, out, N);
}

// Round 10
// 275.533 us; speedup vs baseline: 5.8708x; 1.1642x over previous
//
#include <hip/hip_runtime.h>
#include <hip/hip_bf16.h>
#include <math.h>

typedef short s16x8 __attribute__((ext_vector_type(8)));
typedef float f32x4 __attribute__((ext_vector_type(4)));
typedef float f32x2 __attribute__((ext_vector_type(2)));

__device__ __forceinline__ float bflo(unsigned u) { return __uint_as_float(u << 16); }
__device__ __forceinline__ float bfhi(unsigned u) { return __uint_as_float(u & 0xffff0000u); }
__device__ __forceinline__ unsigned short f2bf(float f) {
    __hip_bfloat16 h = __float2bfloat16(f);
    return __builtin_bit_cast(unsigned short, h);
}
__device__ __forceinline__ f32x4 mfma_bf16(s16x8 a, s16x8 b, f32x4 c) {
    asm("v_mfma_f32_16x16x32_bf16 %0, %1, %2, %0" : "+v"(c) : "v"(a), "v"(b));
    return c;
}
__device__ __forceinline__ f32x2 unpk2(unsigned u) { return (f32x2){bflo(u), bfhi(u)}; }
__device__ __forceinline__ f32x2 plrelu(f32x2 x) {
    return __builtin_elementwise_max(x, x * 0.2f);
}

// ---------------- CSR build: degree+rank in one atomic pass ----------------
__global__ void degree_rank_kernel(const int* __restrict__ dst, int* __restrict__ deg,
                                   int* __restrict__ rank, int E) {
    int e = blockIdx.x * blockDim.x + threadIdx.x;
    if (e < E) rank[e] = atomicAdd(&deg[dst[e]], 1);
}

// 3-kernel hierarchical scan; inner block-scan = proven r8 code (one round/block)
__global__ __launch_bounds__(1024) void scan_part_kernel(const int* __restrict__ deg,
                                                         int* __restrict__ off,
                                                         int* __restrict__ bsum, int n) {
    __shared__ int wsum[16];
    int t = threadIdx.x, lane = t & 63, w = t >> 6;
    int i = blockIdx.x * 4096 + t * 4;
    int4 v = make_int4(0, 0, 0, 0);
    if (i + 3 < n) v = *reinterpret_cast<const int4*>(&deg[i]);
    else {
        if (i < n) v.x = deg[i];
        if (i + 1 < n) v.y = deg[i + 1];
        if (i + 2 < n) v.z = deg[i + 2];
    }
    int tsum = v.x + v.y + v.z + v.w;
    int x = tsum;
    #pragma unroll
    for (int d = 1; d < 64; d <<= 1) { int y = __shfl_up(x, d); if (lane >= d) x += y; }
    if (lane == 63) wsum[w] = x;
    __syncthreads();
    if (t < 16) {
        int y = wsum[t];
        #pragma unroll
        for (int d = 1; d < 16; d <<= 1) { int z = __shfl_up(y, d); if (t >= d) y += z; }
        wsum[t] = y;
    }
    __syncthreads();
    int excl = ((w == 0) ? 0 : wsum[w - 1]) + (x - tsum);
    if (i < n) off[i] = excl;
    if (i + 1 < n) off[i + 1] = excl + v.x;
    if (i + 2 < n) off[i + 2] = excl + v.x + v.y;
    if (i + 3 < n) off[i + 3] = excl + v.x + v.y + v.z;
    if (t == 0) bsum[blockIdx.x] = 0;  // init; real value below
    __syncthreads();
    if (t == 1023) bsum[blockIdx.x] = wsum[15];
}

__global__ __launch_bounds__(64) void scan_tops_kernel(const int* __restrict__ bsum,
                                                       int* __restrict__ tops,
                                                       int* __restrict__ off,
                                                       int nblk, int n) {
    int t = threadIdx.x;
    int v = (t < nblk) ? bsum[t] : 0;
    int x = v;
    #pragma unroll
    for (int d = 1; d < 64; d <<= 1) { int y = __shfl_up(x, d); if (t >= d) x += y; }
    if (t < nblk) tops[t] = x - v;       // exclusive base per block
    if (t == 63) off[n] = x;             // grand total
}

__global__ __launch_bounds__(1024) void scan_add_kernel(int* __restrict__ off,
                                                        const int* __restrict__ tops, int n) {
    int b = blockIdx.x;
    int base = tops[b];
    int i = b * 4096 + threadIdx.x * 4;
    if (i + 3 < n) {
        int4 v = *reinterpret_cast<const int4*>(&off[i]);
        v.x += base; v.y += base; v.z += base; v.w += base;
        *reinterpret_cast<int4*>(&off[i]) = v;
    } else {
        if (i < n) off[i] += base;
        if (i + 1 < n) off[i + 1] += base;
        if (i + 2 < n) off[i + 2] += base;
    }
}

// atomic-free scatter using precomputed ranks
__global__ void scatter_kernel(const int* __restrict__ src, const int* __restrict__ dst,
                               const int* __restrict__ off, const int* __restrict__ rank,
                               int* __restrict__ ssrc, int E) {
    int e = blockIdx.x * blockDim.x + threadIdx.x;
    if (e < E) {
        int d = dst[e];
        ssrc[off[d] + rank[e]] = src[e];
    }
}

// ---------------- weight prep (both layers, one launch) ----------------
__global__ void wt_prep_kernel(const float* __restrict__ Wl1, const float* __restrict__ Wr1,
                               const float* __restrict__ Wl2, const float* __restrict__ Wr2,
                               unsigned short* __restrict__ Wt1, unsigned short* __restrict__ Wt2) {
    int idx = blockIdx.x * 256 + threadIdx.x;
    if (idx < 256 * 128) {
        int n = idx >> 7, k = idx & 127;
        float v = (n < 128) ? Wl1[k * 128 + n] : Wr1[k * 128 + (n - 128)];
        Wt1[idx] = f2bf(v);
    } else if (idx < 256 * 128 + 128 * 128) {
        int j = idx - 256 * 128;
        int n = j >> 7, k = j & 127;
        float v = (n < 64) ? Wl2[k * 64 + n] : Wr2[k * 64 + (n - 64)];
        Wt2[j] = f2bf(v);
    }
}

// ---------------- MFMA dual GEMM (unchanged from r8) ----------------
template <int NOUT, bool AFP32>
__global__ __launch_bounds__(256) void mfma_gemm_kernel(
    const void* __restrict__ A, const unsigned short* __restrict__ Wt,
    unsigned short* __restrict__ Cl, unsigned short* __restrict__ Cr, int nrows) {
    constexpr int HALF = NOUT / 2;
    constexpr int CT = NOUT / 64;
    __shared__ unsigned short As[64 * 128];
    int t = threadIdx.x, lane = t & 63, wave = t >> 6;
    int row_base = blockIdx.x * 64;
    int rows_here = nrows - row_base;
    #pragma unroll
    for (int it = 0; it < 4; ++it) {
        int q = it * 256 + t;
        int r = q >> 4, c8 = q & 15;
        int su = r * 16 + (c8 ^ (r & 7));
        s16x8 v = {0, 0, 0, 0, 0, 0, 0, 0};
        if (r < rows_here) {
            if (AFP32) {
                const float4* g = reinterpret_cast<const float4*>(
                    (const float*)A + ((size_t)(row_base + r)) * 128 + c8 * 8);
                float4 v0 = g[0], v1 = g[1];
                union { s16x8 s; unsigned short u[8]; } pk;
                pk.u[0] = f2bf(v0.x); pk.u[1] = f2bf(v0.y);
                pk.u[2] = f2bf(v0.z); pk.u[3] = f2bf(v0.w);
                pk.u[4] = f2bf(v1.x); pk.u[5] = f2bf(v1.y);
                pk.u[6] = f2bf(v1.z); pk.u[7] = f2bf(v1.w);
                v = pk.s;
            } else {
                v = *reinterpret_cast<const s16x8*>(
                    (const unsigned short*)A + ((size_t)(row_base + r)) * 128 + c8 * 8);
            }
        }
        reinterpret_cast<s16x8*>(As)[su] = v;
    }
    __syncthreads();
    int m16 = lane & 15, kg = lane >> 4;
    int colw = wave * (NOUT / 4);
    s16x8 bfr[CT][4];
    const s16x8* Wt16 = reinterpret_cast<const s16x8*>(Wt);
    #pragma unroll
    for (int ct = 0; ct < CT; ++ct)
        #pragma unroll
        for (int ks = 0; ks < 4; ++ks)
            bfr[ct][ks] = Wt16[(size_t)(colw + ct * 16 + m16) * 16 + ks * 4 + kg];
    f32x4 acc[4][CT];
    #pragma unroll
    for (int rt = 0; rt < 4; ++rt)
        #pragma unroll
        for (int ct = 0; ct < CT; ++ct) acc[rt][ct] = (f32x4){0.f, 0.f, 0.f, 0.f};
    const s16x8* As16 = reinterpret_cast<const s16x8*>(As);
    int sw = m16 & 7;
    #pragma unroll
    for (int rt = 0; rt < 4; ++rt) {
        int abase = (rt * 16 + m16) * 16;
        #pragma unroll
        for (int ks = 0; ks < 4; ++ks) {
            s16x8 af = As16[abase + ((ks * 4 + kg) ^ sw)];
            #pragma unroll
            for (int ct = 0; ct < CT; ++ct)
                acc[rt][ct] = mfma_bf16(af, bfr[ct][ks], acc[rt][ct]);
        }
    }
    int rq = kg * 4;
    #pragma unroll
    for (int rt = 0; rt < 4; ++rt) {
        #pragma unroll
        for (int ct = 0; ct < CT; ++ct) {
            int n = colw + ct * 16 + m16;
            unsigned short* Cp = (n < HALF) ? (Cl + n) : (Cr + (n - HALF));
            int row0 = row_base + rt * 16 + rq;
            #pragma unroll
            for (int i = 0; i < 4; ++i) {
                int row = row0 + i;
                if (row < nrows) Cp[(size_t)row * HALF] = f2bf(acc[rt][ct][i]);
            }
        }
    }
}

// ---------------- GAT layer 1 (unchanged from r8) ----------------
__global__ __launch_bounds__(256) void gat1_kernel(
    const unsigned short* __restrict__ xl, const unsigned short* __restrict__ xr,
    const int* __restrict__ off, const int* __restrict__ ssrc,
    const float* __restrict__ att, const float* __restrict__ bias,
    const float* __restrict__ gamma, const float* __restrict__ beta,
    unsigned short* __restrict__ out, int n) {
    int lane = threadIdx.x & 63;
    int node = blockIdx.x * 4 + (threadIdx.x >> 6);
    if (node >= n) return;
    int h = lane >> 3;
    int i0 = h * 16 + ((lane & 7) << 1);
    f32x2 xrp = unpk2(*reinterpret_cast<const unsigned*>(xr + (size_t)node * 128 + i0));
    f32x2 atp = {att[i0], att[i0 + 1]};
    float s = 0.f;
    f32x2 ac = {0.f, 0.f};
    int beg = off[node], end = off[node + 1];
    int i = beg;
    for (; i + 4 <= end; i += 4) {
        int e0 = ssrc[i], e1 = ssrc[i + 1], e2 = ssrc[i + 2], e3 = ssrc[i + 3];
        unsigned u0 = *reinterpret_cast<const unsigned*>(xl + (size_t)e0 * 128 + i0);
        unsigned u1 = *reinterpret_cast<const unsigned*>(xl + (size_t)e1 * 128 + i0);
        unsigned u2 = *reinterpret_cast<const unsigned*>(xl + (size_t)e2 * 128 + i0);
        unsigned u3 = *reinterpret_cast<const unsigned*>(xl + (size_t)e3 * 128 + i0);
        f32x2 x0 = unpk2(u0), x1 = unpk2(u1), x2 = unpk2(u2), x3 = unpk2(u3);
        f32x2 q0 = plrelu(x0 + xrp) * atp;
        f32x2 q1 = plrelu(x1 + xrp) * atp;
        f32x2 q2 = plrelu(x2 + xrp) * atp;
        f32x2 q3 = plrelu(x3 + xrp) * atp;
        float p0 = q0.x + q0.y, p1 = q1.x + q1.y;
        float p2 = q2.x + q2.y, p3 = q3.x + q3.y;
        #pragma unroll
        for (int d = 1; d < 8; d <<= 1) {
            p0 += __shfl_xor(p0, d); p1 += __shfl_xor(p1, d);
            p2 += __shfl_xor(p2, d); p3 += __shfl_xor(p3, d);
        }
        float w0 = __expf(fminf(p0, 60.f));
        float w1 = __expf(fminf(p1, 60.f));
        float w2 = __expf(fminf(p2, 60.f));
        float w3 = __expf(fminf(p3, 60.f));
        s += (w0 + w1) + (w2 + w3);
        ac += w0 * x0 + w1 * x1;
        ac += w2 * x2 + w3 * x3;
    }
    for (; i < end; ++i) {
        int e = ssrc[i];
        f32x2 xv = unpk2(*reinterpret_cast<const unsigned*>(xl + (size_t)e * 128 + i0));
        f32x2 q = plrelu(xv + xrp) * atp;
        float p = q.x + q.y;
        #pragma unroll
        for (int d = 1; d < 8; d <<= 1) p += __shfl_xor(p, d);
        float w = __expf(fminf(p, 60.f));
        s += w; ac += w * xv;
    }
    float inv = 1.f / (s + 1e-16f);
    float o0 = ac.x * inv + bias[i0];
    float o1 = ac.y * inv + bias[i0 + 1];
    float tsum = o0 + o1;
    #pragma unroll
    for (int d = 1; d < 64; d <<= 1) tsum += __shfl_xor(tsum, d);
    float mu = tsum * (1.f / 128.f);
    float d0 = o0 - mu, d1 = o1 - mu;
    float vsum = d0 * d0 + d1 * d1;
    #pragma unroll
    for (int d = 1; d < 64; d <<= 1) vsum += __shfl_xor(vsum, d);
    float rs = rsqrtf(vsum * (1.f / 128.f) + 1e-5f);
    float y0 = d0 * rs * gamma[i0] + beta[i0];
    float y1 = d1 * rs * gamma[i0 + 1] + beta[i0 + 1];
    y0 = y0 > 0.f ? y0 : expm1f(y0);
    y1 = y1 > 0.f ? y1 : expm1f(y1);
    unsigned pk = (unsigned)f2bf(y0) | ((unsigned)f2bf(y1) << 16);
    *reinterpret_cast<unsigned*>(out + (size_t)node * 128 + i0) = pk;
}

// ---------------- GAT layer 2 (unchanged from r8) ----------------
__global__ __launch_bounds__(256) void gat2_kernel(
    const unsigned short* __restrict__ xl, const unsigned short* __restrict__ xr,
    const int* __restrict__ off, const int* __restrict__ ssrc,
    const float* __restrict__ att, const float* __restrict__ bias,
    const float* __restrict__ gamma, const float* __restrict__ beta,
    float* __restrict__ out, int n) {
    int lane = threadIdx.x & 63;
    int node = blockIdx.x * 4 + (threadIdx.x >> 6);
    if (node >= n) return;
    int half = lane >> 5;
    int c2 = (lane & 31) << 1;
    f32x2 xrp = unpk2(*reinterpret_cast<const unsigned*>(xr + (size_t)node * 64 + c2));
    f32x2 atp = {att[c2], att[c2 + 1]};
    float s = 0.f;
    f32x2 ac = {0.f, 0.f};
    int beg = off[node], end = off[node + 1];
    int i = beg;
    for (; i + 4 <= end; i += 4) {
        int eA = ssrc[i + half], eB = ssrc[i + 2 + half];
        f32x2 xA = unpk2(*reinterpret_cast<const unsigned*>(xl + (size_t)eA * 64 + c2));
        f32x2 xB = unpk2(*reinterpret_cast<const unsigned*>(xl + (size_t)eB * 64 + c2));
        f32x2 qA = plrelu(xA + xrp) * atp;
        f32x2 qB = plrelu(xB + xrp) * atp;
        float pA = qA.x + qA.y, pB = qB.x + qB.y;
        #pragma unroll
        for (int d = 1; d < 32; d <<= 1) {
            pA += __shfl_xor(pA, d); pB += __shfl_xor(pB, d);
        }
        float wA = __expf(fminf(pA, 60.f));
        float wB = __expf(fminf(pB, 60.f));
        s += wA + wB;
        ac += wA * xA + wB * xB;
    }
    for (; i < end; i += 2) {
        int e = i + half;
        bool valid = e < end;
        int se = ssrc[valid ? e : i];
        f32x2 xv = unpk2(*reinterpret_cast<const unsigned*>(xl + (size_t)se * 64 + c2));
        f32x2 q = plrelu(xv + xrp) * atp;
        float p = q.x + q.y;
        #pragma unroll
        for (int d = 1; d < 32; d <<= 1) p += __shfl_xor(p, d);
        float w = valid ? __expf(fminf(p, 60.f)) : 0.f;
        s += w; ac += w * xv;
    }
    s += __shfl_xor(s, 32);
    f32x2 aco = {__shfl_xor(ac.x, 32), __shfl_xor(ac.y, 32)};
    ac += aco;
    float inv = 1.f / (s + 1e-16f);
    float o0 = ac.x * inv + bias[c2];
    float o1 = ac.y * inv + bias[c2 + 1];
    float tsum = o0 + o1;
    #pragma unroll
    for (int d = 1; d < 32; d <<= 1) tsum += __shfl_xor(tsum, d);
    float mu = tsum * (1.f / 64.f);
    float d0 = o0 - mu, d1 = o1 - mu;
    float vsum = d0 * d0 + d1 * d1;
    #pragma unroll
    for (int d = 1; d < 32; d <<= 1) vsum += __shfl_xor(vsum, d);
    float rs = rsqrtf(vsum * (1.f / 64.f) + 1e-5f);
    if (half == 0) {
        float y0 = d0 * rs * gamma[c2] + beta[c2];
        float y1 = d1 * rs * gamma[c2 + 1] + beta[c2 + 1];
        *reinterpret_cast<float2*>(out + (size_t)node * 64 + c2) = make_float2(y0, y1);
    }
}

extern "C" void kernel_launch(void* const* d_in, const int* in_sizes, int n_in,
                              void* d_out, int out_size, void* d_ws, size_t ws_size,
                              hipStream_t stream) {
    const float* x = (const float*)d_in[0];
    const int* ei = (const int*)d_in[1];
    const float* Wl1 = (const float*)d_in[2];
    const float* Wr1 = (const float*)d_in[3];
    const float* att1 = (const float*)d_in[4];
    const float* bias1 = (const float*)d_in[5];
    const float* g1 = (const float*)d_in[6];
    const float* b1 = (const float*)d_in[7];
    const float* Wl2 = (const float*)d_in[8];
    const float* Wr2 = (const float*)d_in[9];
    const float* att2 = (const float*)d_in[10];
    const float* bias2 = (const float*)d_in[11];
    const float* g2 = (const float*)d_in[12];
    const float* b2 = (const float*)d_in[13];
    float* out = (float*)d_out;

    const int N = in_sizes[0] / 128;
    const int E = in_sizes[1] / 2;
    const int* src = ei;
    const int* dstp = ei + E;

    char* p = (char*)d_ws;
    auto alloc = [&](size_t bytes) -> char* {
        char* r = p;
        p += (bytes + 255) & ~(size_t)255;
        return r;
    };
    int* deg = (int*)alloc((size_t)N * 4);
    int* rank = (int*)alloc((size_t)E * 4);
    int* off = (int*)alloc((size_t)(N + 1) * 4);
    int* ssrc = (int*)alloc((size_t)E * 4);
    int* bsum = (int*)alloc(64 * 4);
    int* tops = (int*)alloc(64 * 4);
    unsigned short* Wt1 = (unsigned short*)alloc(256 * 128 * 2);
    unsigned short* Wt2 = (unsigned short*)alloc(128 * 128 * 2);
    unsigned short* bufA = (unsigned short*)alloc((size_t)N * 128 * 2);
    unsigned short* bufB = (unsigned short*)alloc((size_t)N * 128 * 2);
    unsigned short* h1u = (unsigned short*)alloc((size_t)N * 128 * 2);

    const int nblk = (N + 4095) / 4096;

    hipMemsetAsync(deg, 0, (size_t)N * 4, stream);
    degree_rank_kernel<<<(E + 255) / 256, 256, 0, stream>>>(dstp, deg, rank, E);
    wt_prep_kernel<<<(256 * 128 + 128 * 128 + 255) / 256, 256, 0, stream>>>(
        Wl1, Wr1, Wl2, Wr2, Wt1, Wt2);
    scan_part_kernel<<<nblk, 1024, 0, stream>>>(deg, off, bsum, N);
    scan_tops_kernel<<<1, 64, 0, stream>>>(bsum, tops, off, nblk, N);
    scan_add_kernel<<<nblk, 1024, 0, stream>>>(off, tops, N);
    scatter_kernel<<<(E + 255) / 256, 256, 0, stream>>>(src, dstp, off, rank, ssrc, E);

    int gblocks = (N + 63) / 64;
    mfma_gemm_kernel<256, true><<<gblocks, 256, 0, stream>>>(x, Wt1, bufA, bufB, N);
    gat1_kernel<<<(N + 3) / 4, 256, 0, stream>>>(bufA, bufB, off, ssrc, att1, bias1, g1, b1, h1u, N);
    mfma_gemm_kernel<128, false><<<gblocks, 256, 0, stream>>>(h1u, Wt2, bufA, bufB, N);
    gat2_kernel<<<(N + 3) / 4, 256, 0, stream>>>(bufA, bufB, off, ssrc, att2, bias2, g2, b2, out, N);
}

// Round 11
// 268.086 us; speedup vs baseline: 6.0339x; 1.0278x over previous
//
#include <hip/hip_runtime.h>
#include <hip/hip_bf16.h>
#include <math.h>

typedef short s16x8 __attribute__((ext_vector_type(8)));
typedef float f32x4 __attribute__((ext_vector_type(4)));
typedef float f32x2 __attribute__((ext_vector_type(2)));

__device__ __forceinline__ float bflo(unsigned u) { return __uint_as_float(u << 16); }
__device__ __forceinline__ float bfhi(unsigned u) { return __uint_as_float(u & 0xffff0000u); }
__device__ __forceinline__ unsigned short f2bf(float f) {
    __hip_bfloat16 h = __float2bfloat16(f);
    return __builtin_bit_cast(unsigned short, h);
}
__device__ __forceinline__ f32x4 mfma_bf16(s16x8 a, s16x8 b, f32x4 c) {
    asm("v_mfma_f32_16x16x32_bf16 %0, %1, %2, %0" : "+v"(c) : "v"(a), "v"(b));
    return c;
}
__device__ __forceinline__ f32x2 unpk2(unsigned u) { return (f32x2){bflo(u), bfhi(u)}; }
__device__ __forceinline__ f32x2 plrelu(f32x2 x) {
    return __builtin_elementwise_max(x, x * 0.2f);
}
// DPP butterfly add: 0xB1=quad_perm[1,0,3,2], 0x4E=quad_perm[2,3,0,1],
// 0x141=row_half_mirror (sum over 8), 0x140=row_mirror (sum over 16)
template <int CTRL>
__device__ __forceinline__ float dpp_add(float v) {
    int y = __builtin_amdgcn_update_dpp(0, __builtin_bit_cast(int, v), CTRL, 0xf, 0xf, true);
    return v + __builtin_bit_cast(float, y);
}
__device__ __forceinline__ float red8(float p) {
    p = dpp_add<0xB1>(p); p = dpp_add<0x4E>(p); return dpp_add<0x141>(p);
}
__device__ __forceinline__ float red16(float p) {
    p = dpp_add<0xB1>(p); p = dpp_add<0x4E>(p);
    p = dpp_add<0x141>(p); return dpp_add<0x140>(p);
}

// ---------------- CSR build: degree+rank in one atomic pass ----------------
__global__ void degree_rank_kernel(const int* __restrict__ dst, int* __restrict__ deg,
                                   int* __restrict__ rank, int E) {
    int e = blockIdx.x * blockDim.x + threadIdx.x;
    if (e < E) rank[e] = atomicAdd(&deg[dst[e]], 1);
}

// 3-kernel hierarchical scan (proven r10)
__global__ __launch_bounds__(1024) void scan_part_kernel(const int* __restrict__ deg,
                                                         int* __restrict__ off,
                                                         int* __restrict__ bsum, int n) {
    __shared__ int wsum[16];
    int t = threadIdx.x, lane = t & 63, w = t >> 6;
    int i = blockIdx.x * 4096 + t * 4;
    int4 v = make_int4(0, 0, 0, 0);
    if (i + 3 < n) v = *reinterpret_cast<const int4*>(&deg[i]);
    else {
        if (i < n) v.x = deg[i];
        if (i + 1 < n) v.y = deg[i + 1];
        if (i + 2 < n) v.z = deg[i + 2];
    }
    int tsum = v.x + v.y + v.z + v.w;
    int x = tsum;
    #pragma unroll
    for (int d = 1; d < 64; d <<= 1) { int y = __shfl_up(x, d); if (lane >= d) x += y; }
    if (lane == 63) wsum[w] = x;
    __syncthreads();
    if (t < 16) {
        int y = wsum[t];
        #pragma unroll
        for (int d = 1; d < 16; d <<= 1) { int z = __shfl_up(y, d); if (t >= d) y += z; }
        wsum[t] = y;
    }
    __syncthreads();
    int excl = ((w == 0) ? 0 : wsum[w - 1]) + (x - tsum);
    if (i < n) off[i] = excl;
    if (i + 1 < n) off[i + 1] = excl + v.x;
    if (i + 2 < n) off[i + 2] = excl + v.x + v.y;
    if (i + 3 < n) off[i + 3] = excl + v.x + v.y + v.z;
    __syncthreads();
    if (t == 1023) bsum[blockIdx.x] = wsum[15];
}

__global__ __launch_bounds__(64) void scan_tops_kernel(const int* __restrict__ bsum,
                                                       int* __restrict__ tops,
                                                       int* __restrict__ off,
                                                       int nblk, int n) {
    int t = threadIdx.x;
    int v = (t < nblk) ? bsum[t] : 0;
    int x = v;
    #pragma unroll
    for (int d = 1; d < 64; d <<= 1) { int y = __shfl_up(x, d); if (t >= d) x += y; }
    if (t < nblk) tops[t] = x - v;
    if (t == 63) off[n] = x;
}

__global__ __launch_bounds__(1024) void scan_add_kernel(int* __restrict__ off,
                                                        const int* __restrict__ tops, int n) {
    int b = blockIdx.x;
    int base = tops[b];
    int i = b * 4096 + threadIdx.x * 4;
    if (i + 3 < n) {
        int4 v = *reinterpret_cast<const int4*>(&off[i]);
        v.x += base; v.y += base; v.z += base; v.w += base;
        *reinterpret_cast<int4*>(&off[i]) = v;
    } else {
        if (i < n) off[i] += base;
        if (i + 1 < n) off[i + 1] += base;
        if (i + 2 < n) off[i + 2] += base;
    }
}

__global__ void scatter_kernel(const int* __restrict__ src, const int* __restrict__ dst,
                               const int* __restrict__ off, const int* __restrict__ rank,
                               int* __restrict__ ssrc, int E) {
    int e = blockIdx.x * blockDim.x + threadIdx.x;
    if (e < E) {
        int d = dst[e];
        ssrc[off[d] + rank[e]] = src[e];
    }
}

// ---------------- weight prep (both layers, one launch) ----------------
__global__ void wt_prep_kernel(const float* __restrict__ Wl1, const float* __restrict__ Wr1,
                               const float* __restrict__ Wl2, const float* __restrict__ Wr2,
                               unsigned short* __restrict__ Wt1, unsigned short* __restrict__ Wt2) {
    int idx = blockIdx.x * 256 + threadIdx.x;
    if (idx < 256 * 128) {
        int n = idx >> 7, k = idx & 127;
        float v = (n < 128) ? Wl1[k * 128 + n] : Wr1[k * 128 + (n - 128)];
        Wt1[idx] = f2bf(v);
    } else if (idx < 256 * 128 + 128 * 128) {
        int j = idx - 256 * 128;
        int n = j >> 7, k = j & 127;
        float v = (n < 64) ? Wl2[k * 64 + n] : Wr2[k * 64 + (n - 64)];
        Wt2[j] = f2bf(v);
    }
}

// ---------------- MFMA dual GEMM: operand-swapped (C^T in-register) ----------------
// mfma(bfr, af): A/B frag layouts are symmetric (lane&15 + k-part lane>>4), so the
// swap yields D[r=n-offset kg*4+i, c=m16] -> lane owns a ROW, 4 consecutive cols per
// acc reg -> ushort4 stores (16/thread vs 64 scalar).
template <int NOUT, bool AFP32>
__global__ __launch_bounds__(256) void mfma_gemm_kernel(
    const void* __restrict__ A, const unsigned short* __restrict__ Wt,
    unsigned short* __restrict__ Cl, unsigned short* __restrict__ Cr, int nrows) {
    constexpr int HALF = NOUT / 2;
    constexpr int CT = NOUT / 64;
    __shared__ unsigned short As[64 * 128];
    int t = threadIdx.x, lane = t & 63, wave = t >> 6;
    int row_base = blockIdx.x * 64;
    int rows_here = nrows - row_base;
    #pragma unroll
    for (int it = 0; it < 4; ++it) {
        int q = it * 256 + t;
        int r = q >> 4, c8 = q & 15;
        int su = r * 16 + (c8 ^ (r & 7));
        s16x8 v = {0, 0, 0, 0, 0, 0, 0, 0};
        if (r < rows_here) {
            if (AFP32) {
                const float4* g = reinterpret_cast<const float4*>(
                    (const float*)A + ((size_t)(row_base + r)) * 128 + c8 * 8);
                float4 v0 = g[0], v1 = g[1];
                union { s16x8 s; unsigned short u[8]; } pk;
                pk.u[0] = f2bf(v0.x); pk.u[1] = f2bf(v0.y);
                pk.u[2] = f2bf(v0.z); pk.u[3] = f2bf(v0.w);
                pk.u[4] = f2bf(v1.x); pk.u[5] = f2bf(v1.y);
                pk.u[6] = f2bf(v1.z); pk.u[7] = f2bf(v1.w);
                v = pk.s;
            } else {
                v = *reinterpret_cast<const s16x8*>(
                    (const unsigned short*)A + ((size_t)(row_base + r)) * 128 + c8 * 8);
            }
        }
        reinterpret_cast<s16x8*>(As)[su] = v;
    }
    __syncthreads();
    int m16 = lane & 15, kg = lane >> 4;
    int colw = wave * (NOUT / 4);
    s16x8 bfr[CT][4];
    const s16x8* Wt16 = reinterpret_cast<const s16x8*>(Wt);
    #pragma unroll
    for (int ct = 0; ct < CT; ++ct)
        #pragma unroll
        for (int ks = 0; ks < 4; ++ks)
            bfr[ct][ks] = Wt16[(size_t)(colw + ct * 16 + m16) * 16 + ks * 4 + kg];
    f32x4 acc[4][CT];
    #pragma unroll
    for (int rt = 0; rt < 4; ++rt)
        #pragma unroll
        for (int ct = 0; ct < CT; ++ct) acc[rt][ct] = (f32x4){0.f, 0.f, 0.f, 0.f};
    const s16x8* As16 = reinterpret_cast<const s16x8*>(As);
    int sw = m16 & 7;
    #pragma unroll
    for (int rt = 0; rt < 4; ++rt) {
        int abase = (rt * 16 + m16) * 16;
        #pragma unroll
        for (int ks = 0; ks < 4; ++ks) {
            s16x8 af = As16[abase + ((ks * 4 + kg) ^ sw)];
            #pragma unroll
            for (int ct = 0; ct < CT; ++ct)
                acc[rt][ct] = mfma_bf16(bfr[ct][ks], af, acc[rt][ct]);
        }
    }
    // epilogue: lane m16 owns row rt*16+m16; acc regs = cols n = colw+ct*16+kg*4+i
    #pragma unroll
    for (int rt = 0; rt < 4; ++rt) {
        int row = row_base + rt * 16 + m16;
        if (row < nrows) {
            #pragma unroll
            for (int ct = 0; ct < CT; ++ct) {
                int n0 = colw + ct * 16 + kg * 4;
                unsigned short* Cp = (n0 < HALF) ? (Cl + n0) : (Cr + (n0 - HALF));
                ushort4 w4;
                w4.x = f2bf(acc[rt][ct][0]);
                w4.y = f2bf(acc[rt][ct][1]);
                w4.z = f2bf(acc[rt][ct][2]);
                w4.w = f2bf(acc[rt][ct][3]);
                *reinterpret_cast<ushort4*>(&Cp[(size_t)row * HALF]) = w4;
            }
        }
    }
}

// ---------------- GAT layer 1 (r8 layout + DPP 8-lane reduce) ----------------
__global__ __launch_bounds__(256) void gat1_kernel(
    const unsigned short* __restrict__ xl, const unsigned short* __restrict__ xr,
    const int* __restrict__ off, const int* __restrict__ ssrc,
    const float* __restrict__ att, const float* __restrict__ bias,
    const float* __restrict__ gamma, const float* __restrict__ beta,
    unsigned short* __restrict__ out, int n) {
    int lane = threadIdx.x & 63;
    int node = blockIdx.x * 4 + (threadIdx.x >> 6);
    if (node >= n) return;
    int h = lane >> 3;
    int i0 = h * 16 + ((lane & 7) << 1);
    f32x2 xrp = unpk2(*reinterpret_cast<const unsigned*>(xr + (size_t)node * 128 + i0));
    f32x2 atp = {att[i0], att[i0 + 1]};
    float s = 0.f;
    f32x2 ac = {0.f, 0.f};
    int beg = off[node], end = off[node + 1];
    int i = beg;
    for (; i + 4 <= end; i += 4) {
        int e0 = ssrc[i], e1 = ssrc[i + 1], e2 = ssrc[i + 2], e3 = ssrc[i + 3];
        unsigned u0 = *reinterpret_cast<const unsigned*>(xl + (size_t)e0 * 128 + i0);
        unsigned u1 = *reinterpret_cast<const unsigned*>(xl + (size_t)e1 * 128 + i0);
        unsigned u2 = *reinterpret_cast<const unsigned*>(xl + (size_t)e2 * 128 + i0);
        unsigned u3 = *reinterpret_cast<const unsigned*>(xl + (size_t)e3 * 128 + i0);
        f32x2 x0 = unpk2(u0), x1 = unpk2(u1), x2 = unpk2(u2), x3 = unpk2(u3);
        f32x2 q0 = plrelu(x0 + xrp) * atp;
        f32x2 q1 = plrelu(x1 + xrp) * atp;
        f32x2 q2 = plrelu(x2 + xrp) * atp;
        f32x2 q3 = plrelu(x3 + xrp) * atp;
        float p0 = q0.x + q0.y, p1 = q1.x + q1.y;
        float p2 = q2.x + q2.y, p3 = q3.x + q3.y;
        p0 = dpp_add<0xB1>(p0); p1 = dpp_add<0xB1>(p1);
        p2 = dpp_add<0xB1>(p2); p3 = dpp_add<0xB1>(p3);
        p0 = dpp_add<0x4E>(p0); p1 = dpp_add<0x4E>(p1);
        p2 = dpp_add<0x4E>(p2); p3 = dpp_add<0x4E>(p3);
        p0 = dpp_add<0x141>(p0); p1 = dpp_add<0x141>(p1);
        p2 = dpp_add<0x141>(p2); p3 = dpp_add<0x141>(p3);
        float w0 = __expf(fminf(p0, 60.f));
        float w1 = __expf(fminf(p1, 60.f));
        float w2 = __expf(fminf(p2, 60.f));
        float w3 = __expf(fminf(p3, 60.f));
        s += (w0 + w1) + (w2 + w3);
        ac += w0 * x0 + w1 * x1;
        ac += w2 * x2 + w3 * x3;
    }
    for (; i < end; ++i) {
        int e = ssrc[i];
        f32x2 xv = unpk2(*reinterpret_cast<const unsigned*>(xl + (size_t)e * 128 + i0));
        f32x2 q = plrelu(xv + xrp) * atp;
        float p = red8(q.x + q.y);
        float w = __expf(fminf(p, 60.f));
        s += w; ac += w * xv;
    }
    float inv = 1.f / (s + 1e-16f);
    float o0 = ac.x * inv + bias[i0];
    float o1 = ac.y * inv + bias[i0 + 1];
    float tsum = o0 + o1;
    #pragma unroll
    for (int d = 1; d < 64; d <<= 1) tsum += __shfl_xor(tsum, d);
    float mu = tsum * (1.f / 128.f);
    float d0 = o0 - mu, d1 = o1 - mu;
    float vsum = d0 * d0 + d1 * d1;
    #pragma unroll
    for (int d = 1; d < 64; d <<= 1) vsum += __shfl_xor(vsum, d);
    float rs = rsqrtf(vsum * (1.f / 128.f) + 1e-5f);
    float y0 = d0 * rs * gamma[i0] + beta[i0];
    float y1 = d1 * rs * gamma[i0 + 1] + beta[i0 + 1];
    y0 = y0 > 0.f ? y0 : expm1f(y0);
    y1 = y1 > 0.f ? y1 : expm1f(y1);
    unsigned pk = (unsigned)f2bf(y0) | ((unsigned)f2bf(y1) << 16);
    *reinterpret_cast<unsigned*>(out + (size_t)node * 128 + i0) = pk;
}

// ---------------- GAT layer 2: (edge-slot j2=lane>>4, quad q=lane&15) ----------------
// 4 feats/lane, 1x8B gather/lane, 4 edges/iter, all-DPP 16-lane logit reduce,
// float4 coalesced output.
__global__ __launch_bounds__(256) void gat2_kernel(
    const unsigned short* __restrict__ xl, const unsigned short* __restrict__ xr,
    const int* __restrict__ off, const int* __restrict__ ssrc,
    const float* __restrict__ att, const float* __restrict__ bias,
    const float* __restrict__ gamma, const float* __restrict__ beta,
    float* __restrict__ out, int n) {
    int lane = threadIdx.x & 63;
    int node = blockIdx.x * 4 + (threadIdx.x >> 6);
    if (node >= n) return;
    int j2 = lane >> 4;
    int q = lane & 15;
    int fb = q * 4;
    uint2 uxr = *reinterpret_cast<const uint2*>(xr + (size_t)node * 64 + fb);
    f32x2 xr0 = unpk2(uxr.x), xr1 = unpk2(uxr.y);
    float4 at = *reinterpret_cast<const float4*>(att + fb);
    f32x2 at0 = {at.x, at.y}, at1 = {at.z, at.w};
    float s = 0.f;
    f32x2 ac0 = {0.f, 0.f}, ac1 = {0.f, 0.f};
    int beg = off[node], end = off[node + 1];
    for (int base = beg; base < end; base += 4) {
        int idx = base + j2;
        bool valid = idx < end;
        int e = ssrc[valid ? idx : beg];
        uint2 u = *reinterpret_cast<const uint2*>(xl + (size_t)e * 64 + fb);
        f32x2 x0 = unpk2(u.x), x1 = unpk2(u.y);
        f32x2 g0 = plrelu(x0 + xr0) * at0;
        f32x2 g1 = plrelu(x1 + xr1) * at1;
        f32x2 gs = g0 + g1;
        float p = red16(gs.x + gs.y);
        float w = valid ? __expf(fminf(p, 60.f)) : 0.f;
        s += w;
        ac0 += w * x0;
        ac1 += w * x1;
    }
    // reduce partials across the 4 edge slots (xor 16, 32)
    #pragma unroll
    for (int d = 16; d <= 32; d <<= 1) {
        s += __shfl_xor(s, d);
        ac0.x += __shfl_xor(ac0.x, d); ac0.y += __shfl_xor(ac0.y, d);
        ac1.x += __shfl_xor(ac1.x, d); ac1.y += __shfl_xor(ac1.y, d);
    }
    float inv = 1.f / (s + 1e-16f);
    float4 bi = *reinterpret_cast<const float4*>(bias + fb);
    float o0 = ac0.x * inv + bi.x;
    float o1 = ac0.y * inv + bi.y;
    float o2 = ac1.x * inv + bi.z;
    float o3 = ac1.y * inv + bi.w;
    // LayerNorm over 64 (16 lanes x 4 feats, replicated across j2)
    float tsum = red16((o0 + o1) + (o2 + o3));
    float mu = tsum * (1.f / 64.f);
    float d0 = o0 - mu, d1 = o1 - mu, d2 = o2 - mu, d3 = o3 - mu;
    float vs = red16((d0 * d0 + d1 * d1) + (d2 * d2 + d3 * d3));
    float rs = rsqrtf(vs * (1.f / 64.f) + 1e-5f);
    if (j2 == 0) {
        float4 ga = *reinterpret_cast<const float4*>(gamma + fb);
        float4 be = *reinterpret_cast<const float4*>(beta + fb);
        float4 y;
        y.x = d0 * rs * ga.x + be.x;
        y.y = d1 * rs * ga.y + be.y;
        y.z = d2 * rs * ga.z + be.z;
        y.w = d3 * rs * ga.w + be.w;
        *reinterpret_cast<float4*>(out + (size_t)node * 64 + fb) = y;
    }
}

extern "C" void kernel_launch(void* const* d_in, const int* in_sizes, int n_in,
                              void* d_out, int out_size, void* d_ws, size_t ws_size,
                              hipStream_t stream) {
    const float* x = (const float*)d_in[0];
    const int* ei = (const int*)d_in[1];
    const float* Wl1 = (const float*)d_in[2];
    const float* Wr1 = (const float*)d_in[3];
    const float* att1 = (const float*)d_in[4];
    const float* bias1 = (const float*)d_in[5];
    const float* g1 = (const float*)d_in[6];
    const float* b1 = (const float*)d_in[7];
    const float* Wl2 = (const float*)d_in[8];
    const float* Wr2 = (const float*)d_in[9];
    const float* att2 = (const float*)d_in[10];
    const float* bias2 = (const float*)d_in[11];
    const float* g2 = (const float*)d_in[12];
    const float* b2 = (const float*)d_in[13];
    float* out = (float*)d_out;

    const int N = in_sizes[0] / 128;
    const int E = in_sizes[1] / 2;
    const int* src = ei;
    const int* dstp = ei + E;

    char* p = (char*)d_ws;
    auto alloc = [&](size_t bytes) -> char* {
        char* r = p;
        p += (bytes + 255) & ~(size_t)255;
        return r;
    };
    int* deg = (int*)alloc((size_t)N * 4);
    int* rank = (int*)alloc((size_t)E * 4);
    int* off = (int*)alloc((size_t)(N + 1) * 4);
    int* ssrc = (int*)alloc((size_t)E * 4);
    int* bsum = (int*)alloc(64 * 4);
    int* tops = (int*)alloc(64 * 4);
    unsigned short* Wt1 = (unsigned short*)alloc(256 * 128 * 2);
    unsigned short* Wt2 = (unsigned short*)alloc(128 * 128 * 2);
    unsigned short* bufA = (unsigned short*)alloc((size_t)N * 128 * 2);
    unsigned short* bufB = (unsigned short*)alloc((size_t)N * 128 * 2);
    unsigned short* h1u = (unsigned short*)alloc((size_t)N * 128 * 2);

    const int nblk = (N + 4095) / 4096;

    hipMemsetAsync(deg, 0, (size_t)N * 4, stream);
    degree_rank_kernel<<<(E + 255) / 256, 256, 0, stream>>>(dstp, deg, rank, E);
    wt_prep_kernel<<<(256 * 128 + 128 * 128 + 255) / 256, 256, 0, stream>>>(
        Wl1, Wr1, Wl2, Wr2, Wt1, Wt2);
    scan_part_kernel<<<nblk, 1024, 0, stream>>>(deg, off, bsum, N);
    scan_tops_kernel<<<1, 64, 0, stream>>>(bsum, tops, off, nblk, N);
    scan_add_kernel<<<nblk, 1024, 0, stream>>>(off, tops, N);
    scatter_kernel<<<(E + 255) / 256, 256, 0, stream>>>(src, dstp, off, rank, ssrc, E);

    int gblocks = (N + 63) / 64;
    mfma_gemm_kernel<256, true><<<gblocks, 256, 0, stream>>>(x, Wt1, bufA, bufB, N);
    gat1_kernel<<<(N + 3) / 4, 256, 0, stream>>>(bufA, bufB, off, ssrc, att1, bias1, g1, b1, h1u, N);
    mfma_gemm_kernel<128, false><<<gblocks, 256, 0, stream>>>(h1u, Wt2, bufA, bufB, N);
    gat2_kernel<<<(N + 3) / 4, 256, 0, stream>>>(bufA, bufB, off, ssrc, att2, bias2, g2, b2, out, N);
}

// Round 12
// 252.947 us; speedup vs baseline: 6.3950x; 1.0599x over previous
//
#include <hip/hip_runtime.h>
#include <hip/hip_bf16.h>
#include <math.h>

typedef short s16x8 __attribute__((ext_vector_type(8)));
typedef float f32x4 __attribute__((ext_vector_type(4)));
typedef float f32x2 __attribute__((ext_vector_type(2)));

__device__ __forceinline__ float bflo(unsigned u) { return __uint_as_float(u << 16); }
__device__ __forceinline__ float bfhi(unsigned u) { return __uint_as_float(u & 0xffff0000u); }
__device__ __forceinline__ unsigned short f2bf(float f) {
    __hip_bfloat16 h = __float2bfloat16(f);
    return __builtin_bit_cast(unsigned short, h);
}
__device__ __forceinline__ f32x4 mfma_bf16(s16x8 a, s16x8 b, f32x4 c) {
    asm("v_mfma_f32_16x16x32_bf16 %0, %1, %2, %0" : "+v"(c) : "v"(a), "v"(b));
    return c;
}
__device__ __forceinline__ f32x2 unpk2(unsigned u) { return (f32x2){bflo(u), bfhi(u)}; }
__device__ __forceinline__ f32x2 plrelu(f32x2 x) {
    return __builtin_elementwise_max(x, x * 0.2f);
}
template <int CTRL>
__device__ __forceinline__ float dpp_add(float v) {
    int y = __builtin_amdgcn_update_dpp(0, __builtin_bit_cast(int, v), CTRL, 0xf, 0xf, true);
    return v + __builtin_bit_cast(float, y);
}
__device__ __forceinline__ float red8(float p) {
    p = dpp_add<0xB1>(p); p = dpp_add<0x4E>(p); return dpp_add<0x141>(p);
}
__device__ __forceinline__ float red16(float p) {
    p = dpp_add<0xB1>(p); p = dpp_add<0x4E>(p);
    p = dpp_add<0x141>(p); return dpp_add<0x140>(p);
}

// ---------------- K1: weight prep + deg zeroing (fused) ----------------
__global__ void prep_kernel(const float* __restrict__ Wl1, const float* __restrict__ Wr1,
                            const float* __restrict__ Wl2, const float* __restrict__ Wr2,
                            unsigned short* __restrict__ Wt1, unsigned short* __restrict__ Wt2,
                            int* __restrict__ deg, int n) {
    int idx = blockIdx.x * 256 + threadIdx.x;
    if (idx < 256 * 128) {
        int c = idx >> 7, k = idx & 127;
        float v = (c < 128) ? Wl1[k * 128 + c] : Wr1[k * 128 + (c - 128)];
        Wt1[idx] = f2bf(v);
    } else if (idx < 256 * 128 + 128 * 128) {
        int j = idx - 256 * 128;
        int c = j >> 7, k = j & 127;
        float v = (c < 64) ? Wl2[k * 64 + c] : Wr2[k * 64 + (c - 64)];
        Wt2[j] = f2bf(v);
    } else {
        int z = idx - (256 * 128 + 128 * 128);
        int i = z * 4;
        if (i + 3 < n) *reinterpret_cast<int4*>(&deg[i]) = make_int4(0, 0, 0, 0);
        else {
            if (i < n) deg[i] = 0;
            if (i + 1 < n) deg[i + 1] = 0;
            if (i + 2 < n) deg[i + 2] = 0;
        }
    }
}

// ---------------- K2: degree+rank (blocks [0,dblocks)) ∥ gemm256 (rest) ----------------
__global__ __launch_bounds__(256) void degree_gemm_kernel(
    const int* __restrict__ dst, int* __restrict__ deg, int* __restrict__ rank, int E,
    int dblocks,
    const float* __restrict__ A, const unsigned short* __restrict__ Wt,
    unsigned short* __restrict__ Cl, unsigned short* __restrict__ Cr, int nrows) {
    __shared__ unsigned short As[64 * 128];
    if (blockIdx.x < (unsigned)dblocks) {
        int e = blockIdx.x * 256 + threadIdx.x;
        if (e < E) rank[e] = atomicAdd(&deg[dst[e]], 1);
        return;
    }
    constexpr int NOUT = 256, HALF = 128, CT = 4;
    int t = threadIdx.x, lane = t & 63, wave = t >> 6;
    int row_base = (blockIdx.x - dblocks) * 64;
    int rows_here = nrows - row_base;
    #pragma unroll
    for (int it = 0; it < 4; ++it) {
        int q = it * 256 + t;
        int r = q >> 4, c8 = q & 15;
        int su = r * 16 + (c8 ^ (r & 7));
        s16x8 v = {0, 0, 0, 0, 0, 0, 0, 0};
        if (r < rows_here) {
            const float4* g = reinterpret_cast<const float4*>(
                A + ((size_t)(row_base + r)) * 128 + c8 * 8);
            float4 v0 = g[0], v1 = g[1];
            union { s16x8 s; unsigned short u[8]; } pk;
            pk.u[0] = f2bf(v0.x); pk.u[1] = f2bf(v0.y);
            pk.u[2] = f2bf(v0.z); pk.u[3] = f2bf(v0.w);
            pk.u[4] = f2bf(v1.x); pk.u[5] = f2bf(v1.y);
            pk.u[6] = f2bf(v1.z); pk.u[7] = f2bf(v1.w);
            v = pk.s;
        }
        reinterpret_cast<s16x8*>(As)[su] = v;
    }
    __syncthreads();
    int m16 = lane & 15, kg = lane >> 4;
    int colw = wave * (NOUT / 4);
    s16x8 bfr[CT][4];
    const s16x8* Wt16 = reinterpret_cast<const s16x8*>(Wt);
    #pragma unroll
    for (int ct = 0; ct < CT; ++ct)
        #pragma unroll
        for (int ks = 0; ks < 4; ++ks)
            bfr[ct][ks] = Wt16[(size_t)(colw + ct * 16 + m16) * 16 + ks * 4 + kg];
    f32x4 acc[4][CT];
    #pragma unroll
    for (int rt = 0; rt < 4; ++rt)
        #pragma unroll
        for (int ct = 0; ct < CT; ++ct) acc[rt][ct] = (f32x4){0.f, 0.f, 0.f, 0.f};
    const s16x8* As16 = reinterpret_cast<const s16x8*>(As);
    int sw = m16 & 7;
    #pragma unroll
    for (int rt = 0; rt < 4; ++rt) {
        int abase = (rt * 16 + m16) * 16;
        #pragma unroll
        for (int ks = 0; ks < 4; ++ks) {
            s16x8 af = As16[abase + ((ks * 4 + kg) ^ sw)];
            #pragma unroll
            for (int ct = 0; ct < CT; ++ct)
                acc[rt][ct] = mfma_bf16(bfr[ct][ks], af, acc[rt][ct]);
        }
    }
    #pragma unroll
    for (int rt = 0; rt < 4; ++rt) {
        int row = row_base + rt * 16 + m16;
        if (row < nrows) {
            #pragma unroll
            for (int ct = 0; ct < CT; ++ct) {
                int n0 = colw + ct * 16 + kg * 4;
                unsigned short* Cp = (n0 < HALF) ? (Cl + n0) : (Cr + (n0 - HALF));
                ushort4 w4;
                w4.x = f2bf(acc[rt][ct][0]);
                w4.y = f2bf(acc[rt][ct][1]);
                w4.z = f2bf(acc[rt][ct][2]);
                w4.w = f2bf(acc[rt][ct][3]);
                *reinterpret_cast<ushort4*>(&Cp[(size_t)row * HALF]) = w4;
            }
        }
    }
}

// ---------------- scan (part; add with inline tops) ----------------
__global__ __launch_bounds__(1024) void scan_part_kernel(const int* __restrict__ deg,
                                                         int* __restrict__ off,
                                                         int* __restrict__ bsum, int n) {
    __shared__ int wsum[16];
    int t = threadIdx.x, lane = t & 63, w = t >> 6;
    int i = blockIdx.x * 4096 + t * 4;
    int4 v = make_int4(0, 0, 0, 0);
    if (i + 3 < n) v = *reinterpret_cast<const int4*>(&deg[i]);
    else {
        if (i < n) v.x = deg[i];
        if (i + 1 < n) v.y = deg[i + 1];
        if (i + 2 < n) v.z = deg[i + 2];
    }
    int tsum = v.x + v.y + v.z + v.w;
    int x = tsum;
    #pragma unroll
    for (int d = 1; d < 64; d <<= 1) { int y = __shfl_up(x, d); if (lane >= d) x += y; }
    if (lane == 63) wsum[w] = x;
    __syncthreads();
    if (t < 16) {
        int y = wsum[t];
        #pragma unroll
        for (int d = 1; d < 16; d <<= 1) { int z = __shfl_up(y, d); if (t >= d) y += z; }
        wsum[t] = y;
    }
    __syncthreads();
    int excl = ((w == 0) ? 0 : wsum[w - 1]) + (x - tsum);
    if (i < n) off[i] = excl;
    if (i + 1 < n) off[i + 1] = excl + v.x;
    if (i + 2 < n) off[i + 2] = excl + v.x + v.y;
    if (i + 3 < n) off[i + 3] = excl + v.x + v.y + v.z;
    __syncthreads();
    if (t == 1023) bsum[blockIdx.x] = wsum[15];
}

__global__ __launch_bounds__(1024) void scan_add_kernel(int* __restrict__ off,
                                                        const int* __restrict__ bsum,
                                                        int nblk, int n) {
    int b = blockIdx.x;
    int base = 0;
    for (int j = 0; j < b; ++j) base += bsum[j];  // nblk<=13, L2-hot
    int i = b * 4096 + threadIdx.x * 4;
    if (i + 3 < n) {
        int4 v = *reinterpret_cast<const int4*>(&off[i]);
        v.x += base; v.y += base; v.z += base; v.w += base;
        *reinterpret_cast<int4*>(&off[i]) = v;
    } else {
        if (i < n) off[i] += base;
        if (i + 1 < n) off[i + 1] += base;
        if (i + 2 < n) off[i + 2] += base;
    }
    if (b == 0 && threadIdx.x == 0) {
        int tot = 0;
        for (int j = 0; j < nblk; ++j) tot += bsum[j];
        off[n] = tot;
    }
}

__global__ void scatter_kernel(const int* __restrict__ src, const int* __restrict__ dst,
                               const int* __restrict__ off, const int* __restrict__ rank,
                               int* __restrict__ ssrc, int E) {
    int e = blockIdx.x * blockDim.x + threadIdx.x;
    if (e < E) {
        int d = dst[e];
        ssrc[off[d] + rank[e]] = src[e];
    }
}

// ---------------- MFMA dual GEMM for layer 2 (bf16 A) ----------------
__global__ __launch_bounds__(256) void mfma_gemm128_kernel(
    const unsigned short* __restrict__ A, const unsigned short* __restrict__ Wt,
    unsigned short* __restrict__ Cl, unsigned short* __restrict__ Cr, int nrows) {
    constexpr int NOUT = 128, HALF = 64, CT = 2;
    __shared__ unsigned short As[64 * 128];
    int t = threadIdx.x, lane = t & 63, wave = t >> 6;
    int row_base = blockIdx.x * 64;
    int rows_here = nrows - row_base;
    #pragma unroll
    for (int it = 0; it < 4; ++it) {
        int q = it * 256 + t;
        int r = q >> 4, c8 = q & 15;
        int su = r * 16 + (c8 ^ (r & 7));
        s16x8 v = {0, 0, 0, 0, 0, 0, 0, 0};
        if (r < rows_here)
            v = *reinterpret_cast<const s16x8*>(A + ((size_t)(row_base + r)) * 128 + c8 * 8);
        reinterpret_cast<s16x8*>(As)[su] = v;
    }
    __syncthreads();
    int m16 = lane & 15, kg = lane >> 4;
    int colw = wave * (NOUT / 4);
    s16x8 bfr[CT][4];
    const s16x8* Wt16 = reinterpret_cast<const s16x8*>(Wt);
    #pragma unroll
    for (int ct = 0; ct < CT; ++ct)
        #pragma unroll
        for (int ks = 0; ks < 4; ++ks)
            bfr[ct][ks] = Wt16[(size_t)(colw + ct * 16 + m16) * 16 + ks * 4 + kg];
    f32x4 acc[4][CT];
    #pragma unroll
    for (int rt = 0; rt < 4; ++rt)
        #pragma unroll
        for (int ct = 0; ct < CT; ++ct) acc[rt][ct] = (f32x4){0.f, 0.f, 0.f, 0.f};
    const s16x8* As16 = reinterpret_cast<const s16x8*>(As);
    int sw = m16 & 7;
    #pragma unroll
    for (int rt = 0; rt < 4; ++rt) {
        int abase = (rt * 16 + m16) * 16;
        #pragma unroll
        for (int ks = 0; ks < 4; ++ks) {
            s16x8 af = As16[abase + ((ks * 4 + kg) ^ sw)];
            #pragma unroll
            for (int ct = 0; ct < CT; ++ct)
                acc[rt][ct] = mfma_bf16(bfr[ct][ks], af, acc[rt][ct]);
        }
    }
    #pragma unroll
    for (int rt = 0; rt < 4; ++rt) {
        int row = row_base + rt * 16 + m16;
        if (row < nrows) {
            #pragma unroll
            for (int ct = 0; ct < CT; ++ct) {
                int n0 = colw + ct * 16 + kg * 4;
                unsigned short* Cp = (n0 < HALF) ? (Cl + n0) : (Cr + (n0 - HALF));
                ushort4 w4;
                w4.x = f2bf(acc[rt][ct][0]);
                w4.y = f2bf(acc[rt][ct][1]);
                w4.z = f2bf(acc[rt][ct][2]);
                w4.w = f2bf(acc[rt][ct][3]);
                *reinterpret_cast<ushort4*>(&Cp[(size_t)row * HALF]) = w4;
            }
        }
    }
}

// ---------------- GAT layer 1: 1 wave = 1 node (64-thread blocks) ----------------
__global__ __launch_bounds__(64) void gat1_kernel(
    const unsigned short* __restrict__ xl, const unsigned short* __restrict__ xr,
    const int* __restrict__ off, const int* __restrict__ ssrc,
    const float* __restrict__ att, const float* __restrict__ bias,
    const float* __restrict__ gamma, const float* __restrict__ beta,
    unsigned short* __restrict__ out, int n) {
    int lane = threadIdx.x;
    int node = blockIdx.x;
    if (node >= n) return;
    int h = lane >> 3;
    int i0 = h * 16 + ((lane & 7) << 1);
    f32x2 xrp = unpk2(*reinterpret_cast<const unsigned*>(xr + (size_t)node * 128 + i0));
    f32x2 atp = {att[i0], att[i0 + 1]};
    float s = 0.f;
    f32x2 ac = {0.f, 0.f};
    int beg = off[node], end = off[node + 1];
    int i = beg;
    for (; i + 4 <= end; i += 4) {
        int e0 = ssrc[i], e1 = ssrc[i + 1], e2 = ssrc[i + 2], e3 = ssrc[i + 3];
        unsigned u0 = *reinterpret_cast<const unsigned*>(xl + (size_t)e0 * 128 + i0);
        unsigned u1 = *reinterpret_cast<const unsigned*>(xl + (size_t)e1 * 128 + i0);
        unsigned u2 = *reinterpret_cast<const unsigned*>(xl + (size_t)e2 * 128 + i0);
        unsigned u3 = *reinterpret_cast<const unsigned*>(xl + (size_t)e3 * 128 + i0);
        f32x2 x0 = unpk2(u0), x1 = unpk2(u1), x2 = unpk2(u2), x3 = unpk2(u3);
        f32x2 q0 = plrelu(x0 + xrp) * atp;
        f32x2 q1 = plrelu(x1 + xrp) * atp;
        f32x2 q2 = plrelu(x2 + xrp) * atp;
        f32x2 q3 = plrelu(x3 + xrp) * atp;
        float p0 = q0.x + q0.y, p1 = q1.x + q1.y;
        float p2 = q2.x + q2.y, p3 = q3.x + q3.y;
        p0 = dpp_add<0xB1>(p0); p1 = dpp_add<0xB1>(p1);
        p2 = dpp_add<0xB1>(p2); p3 = dpp_add<0xB1>(p3);
        p0 = dpp_add<0x4E>(p0); p1 = dpp_add<0x4E>(p1);
        p2 = dpp_add<0x4E>(p2); p3 = dpp_add<0x4E>(p3);
        p0 = dpp_add<0x141>(p0); p1 = dpp_add<0x141>(p1);
        p2 = dpp_add<0x141>(p2); p3 = dpp_add<0x141>(p3);
        float w0 = __expf(fminf(p0, 60.f));
        float w1 = __expf(fminf(p1, 60.f));
        float w2 = __expf(fminf(p2, 60.f));
        float w3 = __expf(fminf(p3, 60.f));
        s += (w0 + w1) + (w2 + w3);
        ac += w0 * x0 + w1 * x1;
        ac += w2 * x2 + w3 * x3;
    }
    for (; i < end; ++i) {
        int e = ssrc[i];
        f32x2 xv = unpk2(*reinterpret_cast<const unsigned*>(xl + (size_t)e * 128 + i0));
        f32x2 q = plrelu(xv + xrp) * atp;
        float p = red8(q.x + q.y);
        float w = __expf(fminf(p, 60.f));
        s += w; ac += w * xv;
    }
    float inv = 1.f / (s + 1e-16f);
    float o0 = ac.x * inv + bias[i0];
    float o1 = ac.y * inv + bias[i0 + 1];
    float tsum = o0 + o1;
    #pragma unroll
    for (int d = 1; d < 64; d <<= 1) tsum += __shfl_xor(tsum, d);
    float mu = tsum * (1.f / 128.f);
    float d0 = o0 - mu, d1 = o1 - mu;
    float vsum = d0 * d0 + d1 * d1;
    #pragma unroll
    for (int d = 1; d < 64; d <<= 1) vsum += __shfl_xor(vsum, d);
    float rs = rsqrtf(vsum * (1.f / 128.f) + 1e-5f);
    float y0 = d0 * rs * gamma[i0] + beta[i0];
    float y1 = d1 * rs * gamma[i0 + 1] + beta[i0 + 1];
    y0 = y0 > 0.f ? y0 : expm1f(y0);
    y1 = y1 > 0.f ? y1 : expm1f(y1);
    unsigned pk = (unsigned)f2bf(y0) | ((unsigned)f2bf(y1) << 16);
    *reinterpret_cast<unsigned*>(out + (size_t)node * 128 + i0) = pk;
}

// ---------------- GAT layer 2: 1 wave = 1 node (64-thread blocks) ----------------
__global__ __launch_bounds__(64) void gat2_kernel(
    const unsigned short* __restrict__ xl, const unsigned short* __restrict__ xr,
    const int* __restrict__ off, const int* __restrict__ ssrc,
    const float* __restrict__ att, const float* __restrict__ bias,
    const float* __restrict__ gamma, const float* __restrict__ beta,
    float* __restrict__ out, int n) {
    int lane = threadIdx.x;
    int node = blockIdx.x;
    if (node >= n) return;
    int j2 = lane >> 4;
    int q = lane & 15;
    int fb = q * 4;
    uint2 uxr = *reinterpret_cast<const uint2*>(xr + (size_t)node * 64 + fb);
    f32x2 xr0 = unpk2(uxr.x), xr1 = unpk2(uxr.y);
    float4 at = *reinterpret_cast<const float4*>(att + fb);
    f32x2 at0 = {at.x, at.y}, at1 = {at.z, at.w};
    float s = 0.f;
    f32x2 ac0 = {0.f, 0.f}, ac1 = {0.f, 0.f};
    int beg = off[node], end = off[node + 1];
    for (int base = beg; base < end; base += 4) {
        int idx = base + j2;
        bool valid = idx < end;
        int e = ssrc[valid ? idx : beg];
        uint2 u = *reinterpret_cast<const uint2*>(xl + (size_t)e * 64 + fb);
        f32x2 x0 = unpk2(u.x), x1 = unpk2(u.y);
        f32x2 g0 = plrelu(x0 + xr0) * at0;
        f32x2 g1 = plrelu(x1 + xr1) * at1;
        f32x2 gs = g0 + g1;
        float p = red16(gs.x + gs.y);
        float w = valid ? __expf(fminf(p, 60.f)) : 0.f;
        s += w;
        ac0 += w * x0;
        ac1 += w * x1;
    }
    #pragma unroll
    for (int d = 16; d <= 32; d <<= 1) {
        s += __shfl_xor(s, d);
        ac0.x += __shfl_xor(ac0.x, d); ac0.y += __shfl_xor(ac0.y, d);
        ac1.x += __shfl_xor(ac1.x, d); ac1.y += __shfl_xor(ac1.y, d);
    }
    float inv = 1.f / (s + 1e-16f);
    float4 bi = *reinterpret_cast<const float4*>(bias + fb);
    float o0 = ac0.x * inv + bi.x;
    float o1 = ac0.y * inv + bi.y;
    float o2 = ac1.x * inv + bi.z;
    float o3 = ac1.y * inv + bi.w;
    float tsum = red16((o0 + o1) + (o2 + o3));
    float mu = tsum * (1.f / 64.f);
    float d0 = o0 - mu, d1 = o1 - mu, d2 = o2 - mu, d3 = o3 - mu;
    float vs = red16((d0 * d0 + d1 * d1) + (d2 * d2 + d3 * d3));
    float rs = rsqrtf(vs * (1.f / 64.f) + 1e-5f);
    if (j2 == 0) {
        float4 ga = *reinterpret_cast<const float4*>(gamma + fb);
        float4 be = *reinterpret_cast<const float4*>(beta + fb);
        float4 y;
        y.x = d0 * rs * ga.x + be.x;
        y.y = d1 * rs * ga.y + be.y;
        y.z = d2 * rs * ga.z + be.z;
        y.w = d3 * rs * ga.w + be.w;
        *reinterpret_cast<float4*>(out + (size_t)node * 64 + fb) = y;
    }
}

extern "C" void kernel_launch(void* const* d_in, const int* in_sizes, int n_in,
                              void* d_out, int out_size, void* d_ws, size_t ws_size,
                              hipStream_t stream) {
    const float* x = (const float*)d_in[0];
    const int* ei = (const int*)d_in[1];
    const float* Wl1 = (const float*)d_in[2];
    const float* Wr1 = (const float*)d_in[3];
    const float* att1 = (const float*)d_in[4];
    const float* bias1 = (const float*)d_in[5];
    const float* g1 = (const float*)d_in[6];
    const float* b1 = (const float*)d_in[7];
    const float* Wl2 = (const float*)d_in[8];
    const float* Wr2 = (const float*)d_in[9];
    const float* att2 = (const float*)d_in[10];
    const float* bias2 = (const float*)d_in[11];
    const float* g2 = (const float*)d_in[12];
    const float* b2 = (const float*)d_in[13];
    float* out = (float*)d_out;

    const int N = in_sizes[0] / 128;
    const int E = in_sizes[1] / 2;
    const int* src = ei;
    const int* dstp = ei + E;

    char* p = (char*)d_ws;
    auto alloc = [&](size_t bytes) -> char* {
        char* r = p;
        p += (bytes + 255) & ~(size_t)255;
        return r;
    };
    int* deg = (int*)alloc((size_t)N * 4);
    int* rank = (int*)alloc((size_t)E * 4);
    int* off = (int*)alloc((size_t)(N + 1) * 4);
    int* ssrc = (int*)alloc((size_t)E * 4);
    int* bsum = (int*)alloc(64 * 4);
    unsigned short* Wt1 = (unsigned short*)alloc(256 * 128 * 2);
    unsigned short* Wt2 = (unsigned short*)alloc(128 * 128 * 2);
    unsigned short* bufA = (unsigned short*)alloc((size_t)N * 128 * 2);
    unsigned short* bufB = (unsigned short*)alloc((size_t)N * 128 * 2);
    unsigned short* h1u = (unsigned short*)alloc((size_t)N * 128 * 2);

    const int nblk = (N + 4095) / 4096;
    const int gblocks = (N + 63) / 64;
    const int dblocks = (E + 255) / 256;
    const int prep_threads = 256 * 128 + 128 * 128 + (N + 3) / 4;

    prep_kernel<<<(prep_threads + 255) / 256, 256, 0, stream>>>(
        Wl1, Wr1, Wl2, Wr2, Wt1, Wt2, deg, N);
    degree_gemm_kernel<<<dblocks + gblocks, 256, 0, stream>>>(
        dstp, deg, rank, E, dblocks, x, Wt1, bufA, bufB, N);
    scan_part_kernel<<<nblk, 1024, 0, stream>>>(deg, off, bsum, N);
    scan_add_kernel<<<nblk, 1024, 0, stream>>>(off, bsum, nblk, N);
    scatter_kernel<<<(E + 255) / 256, 256, 0, stream>>>(src, dstp, off, rank, ssrc, E);
    gat1_kernel<<<N, 64, 0, stream>>>(bufA, bufB, off, ssrc, att1, bias1, g1, b1, h1u, N);
    mfma_gemm128_kernel<<<gblocks, 256, 0, stream>>>(h1u, Wt2, bufA, bufB, N);
    gat2_kernel<<<N, 64, 0, stream>>>(bufA, bufB, off, ssrc, att2, bias2, g2, b2, out, N);
}